// Round 1
// baseline (1492.886 us; speedup 1.0000x reference)
//
#include <hip/hip_runtime.h>
#include <cmath>

#define B_ 2
#define N_ 2048
#define D_ 1024
#define H_ 16
#define DH_ 64
#define EPS_ 1e-8f

// ---------------- RMS-like norm: xn = x / max(||x||/sqrt(D), eps) * gamma ----------------
__global__ __launch_bounds__(256) void rmsnorm_kernel(const float* __restrict__ x,
                                                      const float* __restrict__ gamma,
                                                      float* __restrict__ xn) {
    const int row = blockIdx.x;
    const float4 v = reinterpret_cast<const float4*>(x + (size_t)row * D_)[threadIdx.x];
    float ss = v.x * v.x + v.y * v.y + v.z * v.z + v.w * v.w;
    #pragma unroll
    for (int off = 32; off; off >>= 1) ss += __shfl_xor(ss, off, 64);
    __shared__ float wss[4];
    const int wid = threadIdx.x >> 6;
    if ((threadIdx.x & 63) == 0) wss[wid] = ss;
    __syncthreads();
    const float tot = wss[0] + wss[1] + wss[2] + wss[3];
    const float norm = sqrtf(tot * (1.0f / D_));
    const float inv = 1.0f / fmaxf(norm, EPS_);
    const float4 g = reinterpret_cast<const float4*>(gamma)[threadIdx.x];
    float4 o;
    o.x = v.x * inv * g.x;
    o.y = v.y * inv * g.y;
    o.z = v.z * inv * g.z;
    o.w = v.w * inv * g.w;
    reinterpret_cast<float4*>(xn + (size_t)row * D_)[threadIdx.x] = o;
}

// ---------------- fp32 tiled GEMM: C = A(MxK) @ B(KxN) [+ bias] ----------------
// 64x64 tile, BK=16, 256 threads, 4x4 per thread.
template <bool BIAS>
__global__ __launch_bounds__(256) void gemm_kernel(const float* __restrict__ A,
                                                   const float* __restrict__ Bm,
                                                   const float* __restrict__ bias,
                                                   float* __restrict__ C,
                                                   int M, int N, int K) {
    __shared__ float As[16][68];   // A^T tile: As[k][m], pad->16B-aligned rows, conflict-free
    __shared__ float Bs[16][64];
    const int tid = threadIdx.x;
    const int tx = tid & 15, ty = tid >> 4;
    const int m0 = blockIdx.y * 64, n0 = blockIdx.x * 64;
    const int am = tid >> 2;
    const int ak = (tid & 3) * 4;
    const int bk = tid >> 4;
    const int bn = (tid & 15) * 4;
    float acc[4][4] = {};
    for (int k0 = 0; k0 < K; k0 += 16) {
        const float4 a = *reinterpret_cast<const float4*>(A + (size_t)(m0 + am) * K + k0 + ak);
        As[ak + 0][am] = a.x;
        As[ak + 1][am] = a.y;
        As[ak + 2][am] = a.z;
        As[ak + 3][am] = a.w;
        *reinterpret_cast<float4*>(&Bs[bk][bn]) =
            *reinterpret_cast<const float4*>(Bm + (size_t)(k0 + bk) * N + n0 + bn);
        __syncthreads();
        #pragma unroll
        for (int kk = 0; kk < 16; ++kk) {
            const float4 av = *reinterpret_cast<const float4*>(&As[kk][ty * 4]);
            const float4 bv = *reinterpret_cast<const float4*>(&Bs[kk][tx * 4]);
            acc[0][0] += av.x * bv.x; acc[0][1] += av.x * bv.y; acc[0][2] += av.x * bv.z; acc[0][3] += av.x * bv.w;
            acc[1][0] += av.y * bv.x; acc[1][1] += av.y * bv.y; acc[1][2] += av.y * bv.z; acc[1][3] += av.y * bv.w;
            acc[2][0] += av.z * bv.x; acc[2][1] += av.z * bv.y; acc[2][2] += av.z * bv.z; acc[2][3] += av.z * bv.w;
            acc[3][0] += av.w * bv.x; acc[3][1] += av.w * bv.y; acc[3][2] += av.w * bv.z; acc[3][3] += av.w * bv.w;
        }
        __syncthreads();
    }
    float4 bb = make_float4(0.f, 0.f, 0.f, 0.f);
    if (BIAS) bb = *reinterpret_cast<const float4*>(bias + n0 + tx * 4);
    #pragma unroll
    for (int i = 0; i < 4; ++i) {
        const int row = m0 + ty * 4 + i;
        float4 o;
        o.x = acc[i][0] + bb.x;
        o.y = acc[i][1] + bb.y;
        o.z = acc[i][2] + bb.z;
        o.w = acc[i][3] + bb.w;
        *reinterpret_cast<float4*>(C + (size_t)row * N + n0 + tx * 4) = o;
    }
}

// ---------------- in-place RoPE on head-interleaved rows ----------------
// t layout: rows (b*N+n) of length row_len; head h occupies cols [h*64, h*64+64)
// out[d]    = scale*(x[d]*cos(f[d])   - x[d+32]*sin(f[d]))     d in [0,32)
// out[d+32] = scale*(x[d+32]*cos(f2)  + x[d]*sin(f2)),  f2 = f[d+32]
__global__ __launch_bounds__(256) void rope_kernel(float* __restrict__ t,
                                                   const float* __restrict__ pos,
                                                   int row_len, float scale) {
    const int idx = blockIdx.x * 256 + threadIdx.x;  // B*N*H*32 total
    const int d = idx & 31;
    const int h = (idx >> 5) & 15;
    const int n = (idx >> 9) & (N_ - 1);
    const int b = idx >> 20;
    const size_t base = (size_t)(b * N_ + n) * row_len + h * 64;
    const float x1 = t[base + d];
    const float x2 = t[base + 32 + d];
    const float f1 = pos[n * 64 + d];
    const float f2 = pos[n * 64 + 32 + d];
    const float o1 = scale * (x1 * cosf(f1) - x2 * sinf(f1));
    const float o2 = scale * (x2 * cosf(f2) + x1 * sinf(f2));
    t[base + d] = o1;
    t[base + 32 + d] = o2;
}

// ---------------- causal flash attention (fp32) ----------------
// grid (N/16, B*H); 256 threads = 4 waves; each wave owns 4 query rows.
// K/V read strided straight out of the kv projection buffer (row_len 2048).
__global__ __launch_bounds__(256) void attn_kernel(const float* __restrict__ q,
                                                   const float* __restrict__ kv,
                                                   float* __restrict__ att) {
    const int bh = blockIdx.y;
    const int b = bh >> 4, h = bh & 15;
    const int qb = blockIdx.x * 16;
    const int tid = threadIdx.x;
    const int lane = tid & 63;
    const int w = tid >> 6;

    __shared__ float Qs[16][64];
    __shared__ float Ks[64][65];
    __shared__ float Vs[64][65];
    __shared__ float ps[4][4][64];

    #pragma unroll
    for (int i = 0; i < 4; ++i) {
        const int e = i * 256 + tid;
        const int r = e >> 6, d = e & 63;
        Qs[r][d] = q[(size_t)(b * N_ + qb + r) * 1024 + h * 64 + d];
    }
    __syncthreads();

    float mr[4] = {-1e30f, -1e30f, -1e30f, -1e30f};
    float lr[4] = {0.f, 0.f, 0.f, 0.f};
    float ov[4] = {0.f, 0.f, 0.f, 0.f};
    const int r0 = w * 4;
    const int tmax = (qb + 15) >> 6;

    for (int t = 0; t <= tmax; ++t) {
        const int jb = t * 64;
        #pragma unroll
        for (int i = 0; i < 16; ++i) {
            const int e = i * 256 + tid;
            const int jr = e >> 6, d = e & 63;
            const size_t base = (size_t)(b * N_ + jb + jr) * 2048 + h * 64 + d;
            Ks[jr][d] = kv[base];
            Vs[jr][d] = kv[base + 1024];
        }
        __syncthreads();

        // scores for 4 rows, lane = key index j within tile
        float s[4] = {0.f, 0.f, 0.f, 0.f};
        #pragma unroll 16
        for (int d = 0; d < 64; ++d) {
            const float kd = Ks[lane][d];
            s[0] += Qs[r0 + 0][d] * kd;
            s[1] += Qs[r0 + 1][d] * kd;
            s[2] += Qs[r0 + 2][d] * kd;
            s[3] += Qs[r0 + 3][d] * kd;
        }
        float corr[4];
        #pragma unroll
        for (int rr = 0; rr < 4; ++rr) {
            const int n = qb + r0 + rr;
            if (jb > n) {  // entire tile masked for this row
                corr[rr] = 1.0f;
                ps[w][rr][lane] = 0.0f;
                continue;
            }
            float sv = (jb + lane <= n) ? s[rr] : -1e30f;
            float smax = sv;
            #pragma unroll
            for (int off = 32; off; off >>= 1) smax = fmaxf(smax, __shfl_xor(smax, off, 64));
            const float mnew = fmaxf(mr[rr], smax);
            const float c = __expf(mr[rr] - mnew);
            const float p = __expf(sv - mnew);
            float psum = p;
            #pragma unroll
            for (int off = 32; off; off >>= 1) psum += __shfl_xor(psum, off, 64);
            lr[rr] = lr[rr] * c + psum;
            mr[rr] = mnew;
            corr[rr] = c;
            ps[w][rr][lane] = p;
        }
        ov[0] *= corr[0]; ov[1] *= corr[1]; ov[2] *= corr[2]; ov[3] *= corr[3];
        // PV: lane = head dim d
        #pragma unroll 16
        for (int j = 0; j < 64; ++j) {
            const float vd = Vs[j][lane];
            ov[0] += ps[w][0][j] * vd;
            ov[1] += ps[w][1][j] * vd;
            ov[2] += ps[w][2][j] * vd;
            ov[3] += ps[w][3][j] * vd;
        }
        __syncthreads();
    }
    #pragma unroll
    for (int rr = 0; rr < 4; ++rr) {
        const int n = qb + r0 + rr;
        att[(size_t)(b * N_ + n) * 1024 + h * 64 + lane] = ov[rr] / lr[rr];
    }
}

extern "C" void kernel_launch(void* const* d_in, const int* in_sizes, int n_in,
                              void* d_out, int out_size, void* d_ws, size_t ws_size,
                              hipStream_t stream) {
    const float* x     = (const float*)d_in[0];
    const float* pos   = (const float*)d_in[1];
    const float* gamma = (const float*)d_in[2];
    const float* Wq    = (const float*)d_in[3];
    const float* Wkv   = (const float*)d_in[4];
    const float* Wo    = (const float*)d_in[5];
    const float* bo    = (const float*)d_in[6];
    float* out = (float*)d_out;
    float* ws  = (float*)d_ws;

    float* xn  = ws;                             // 4M floats; reused as attention output
    float* q   = ws + (size_t)4 * 1024 * 1024;   // 4M floats
    float* kv  = ws + (size_t)8 * 1024 * 1024;   // 8M floats
    float* att = xn;

    const int ROWS = B_ * N_;  // 4096

    rmsnorm_kernel<<<ROWS, 256, 0, stream>>>(x, gamma, xn);

    gemm_kernel<false><<<dim3(1024 / 64, ROWS / 64), 256, 0, stream>>>(
        xn, Wq, nullptr, q, ROWS, 1024, 1024);
    gemm_kernel<false><<<dim3(2048 / 64, ROWS / 64), 256, 0, stream>>>(
        x, Wkv, nullptr, kv, ROWS, 2048, 1024);

    // q scaled by DH^-0.5 inside RoPE (linear, commutes with rotation)
    rope_kernel<<<(B_ * N_ * H_ * 32) / 256, 256, 0, stream>>>(q, pos, 1024, 0.125f);
    rope_kernel<<<(B_ * N_ * H_ * 32) / 256, 256, 0, stream>>>(kv, pos, 2048, 1.0f);

    attn_kernel<<<dim3(N_ / 16, B_ * H_), 256, 0, stream>>>(q, kv, att);

    gemm_kernel<true><<<dim3(1024 / 64, ROWS / 64), 256, 0, stream>>>(
        att, Wo, bo, out, ROWS, 1024, 1024);
}

// Round 2
// 730.742 us; speedup vs baseline: 2.0430x; 2.0430x over previous
//
#include <hip/hip_runtime.h>
#include <cmath>

#define B_ 2
#define N_ 2048
#define D_ 1024
#define H_ 16
#define DH_ 64
#define EPS_ 1e-8f

typedef __attribute__((ext_vector_type(8))) short short8;
typedef __attribute__((ext_vector_type(4))) float f32x4;

__device__ __forceinline__ unsigned short f2bf(float f) {
    union { float f; unsigned u; } x;
    x.f = f;
    unsigned r = x.u + 0x7FFFu + ((x.u >> 16) & 1u);
    return (unsigned short)(r >> 16);
}

__device__ __forceinline__ short8 pack8(float4 a, float4 b) {
    short8 r;
    r[0] = (short)f2bf(a.x); r[1] = (short)f2bf(a.y);
    r[2] = (short)f2bf(a.z); r[3] = (short)f2bf(a.w);
    r[4] = (short)f2bf(b.x); r[5] = (short)f2bf(b.y);
    r[6] = (short)f2bf(b.z); r[7] = (short)f2bf(b.w);
    return r;
}

// ---------------- RMS-like norm ----------------
__global__ __launch_bounds__(256) void rmsnorm_kernel(const float* __restrict__ x,
                                                      const float* __restrict__ gamma,
                                                      float* __restrict__ xn) {
    const int row = blockIdx.x;
    const float4 v = reinterpret_cast<const float4*>(x + (size_t)row * D_)[threadIdx.x];
    float ss = v.x * v.x + v.y * v.y + v.z * v.z + v.w * v.w;
    #pragma unroll
    for (int off = 32; off; off >>= 1) ss += __shfl_xor(ss, off, 64);
    __shared__ float wss[4];
    const int wid = threadIdx.x >> 6;
    if ((threadIdx.x & 63) == 0) wss[wid] = ss;
    __syncthreads();
    const float tot = wss[0] + wss[1] + wss[2] + wss[3];
    const float norm = sqrtf(tot * (1.0f / D_));
    const float inv = 1.0f / fmaxf(norm, EPS_);
    const float4 g = reinterpret_cast<const float4*>(gamma)[threadIdx.x];
    float4 o;
    o.x = v.x * inv * g.x;
    o.y = v.y * inv * g.y;
    o.z = v.z * inv * g.z;
    o.w = v.w * inv * g.w;
    reinterpret_cast<float4*>(xn + (size_t)row * D_)[threadIdx.x] = o;
}

// ---------------- fp32 tiled GEMM (unchanged this round) ----------------
template <bool BIAS>
__global__ __launch_bounds__(256) void gemm_kernel(const float* __restrict__ A,
                                                   const float* __restrict__ Bm,
                                                   const float* __restrict__ bias,
                                                   float* __restrict__ C,
                                                   int M, int N, int K) {
    __shared__ float As[16][68];
    __shared__ float Bs[16][64];
    const int tid = threadIdx.x;
    const int tx = tid & 15, ty = tid >> 4;
    const int m0 = blockIdx.y * 64, n0 = blockIdx.x * 64;
    const int am = tid >> 2;
    const int ak = (tid & 3) * 4;
    const int bk = tid >> 4;
    const int bn = (tid & 15) * 4;
    float acc[4][4] = {};
    for (int k0 = 0; k0 < K; k0 += 16) {
        const float4 a = *reinterpret_cast<const float4*>(A + (size_t)(m0 + am) * K + k0 + ak);
        As[ak + 0][am] = a.x;
        As[ak + 1][am] = a.y;
        As[ak + 2][am] = a.z;
        As[ak + 3][am] = a.w;
        *reinterpret_cast<float4*>(&Bs[bk][bn]) =
            *reinterpret_cast<const float4*>(Bm + (size_t)(k0 + bk) * N + n0 + bn);
        __syncthreads();
        #pragma unroll
        for (int kk = 0; kk < 16; ++kk) {
            const float4 av = *reinterpret_cast<const float4*>(&As[kk][ty * 4]);
            const float4 bv = *reinterpret_cast<const float4*>(&Bs[kk][tx * 4]);
            acc[0][0] += av.x * bv.x; acc[0][1] += av.x * bv.y; acc[0][2] += av.x * bv.z; acc[0][3] += av.x * bv.w;
            acc[1][0] += av.y * bv.x; acc[1][1] += av.y * bv.y; acc[1][2] += av.y * bv.z; acc[1][3] += av.y * bv.w;
            acc[2][0] += av.z * bv.x; acc[2][1] += av.z * bv.y; acc[2][2] += av.z * bv.z; acc[2][3] += av.z * bv.w;
            acc[3][0] += av.w * bv.x; acc[3][1] += av.w * bv.y; acc[3][2] += av.w * bv.z; acc[3][3] += av.w * bv.w;
        }
        __syncthreads();
    }
    float4 bb = make_float4(0.f, 0.f, 0.f, 0.f);
    if (BIAS) bb = *reinterpret_cast<const float4*>(bias + n0 + tx * 4);
    #pragma unroll
    for (int i = 0; i < 4; ++i) {
        const int row = m0 + ty * 4 + i;
        float4 o;
        o.x = acc[i][0] + bb.x;
        o.y = acc[i][1] + bb.y;
        o.z = acc[i][2] + bb.z;
        o.w = acc[i][3] + bb.w;
        *reinterpret_cast<float4*>(C + (size_t)row * N + n0 + tx * 4) = o;
    }
}

// ---------------- in-place RoPE ----------------
__global__ __launch_bounds__(256) void rope_kernel(float* __restrict__ t,
                                                   const float* __restrict__ pos,
                                                   int row_len, float scale) {
    const int idx = blockIdx.x * 256 + threadIdx.x;
    const int d = idx & 31;
    const int h = (idx >> 5) & 15;
    const int n = (idx >> 9) & (N_ - 1);
    const int b = idx >> 20;
    const size_t base = (size_t)(b * N_ + n) * row_len + h * 64;
    const float x1 = t[base + d];
    const float x2 = t[base + 32 + d];
    const float f1 = pos[n * 64 + d];
    const float f2 = pos[n * 64 + 32 + d];
    const float o1 = scale * (x1 * cosf(f1) - x2 * sinf(f1));
    const float o2 = scale * (x2 * cosf(f2) + x1 * sinf(f2));
    t[base + d] = o1;
    t[base + 32 + d] = o2;
}

// ---------------- bf16 MFMA causal flash attention ----------------
// grid (N/64, B*H); 256 threads = 4 waves; wave w owns query rows qb+w*16 .. +15.
// mfma_f32_16x16x32_bf16 layouts (verified, guide §3):
//   A: row = lane&15, k = (lane>>4)*8 + j   (8 contiguous k per lane)
//   B: col = lane&15, k = (lane>>4)*8 + j
//   C/D: col = lane&15, row = (lane>>4)*4 + reg
__global__ __launch_bounds__(256) void attn_mfma_kernel(const float* __restrict__ q,
                                                        const float* __restrict__ kv,
                                                        float* __restrict__ att) {
    const int bh = blockIdx.y;
    const int b = bh >> 4, h = bh & 15;
    const int qb = blockIdx.x * 64;
    const int tid = threadIdx.x;
    const int lane = tid & 63;
    const int w = tid >> 6;

    __shared__ __align__(16) unsigned short Ks[64 * 64];       // [key][d] bf16, swizzled
    __shared__ __align__(16) unsigned short Vt[64 * 64];       // [d][key] bf16, swizzled
    __shared__ __align__(16) unsigned short Ps[4][16 * 64];    // per-wave P [row][key], swizzled
    char* const Ksc = (char*)Ks;
    char* const Vtc = (char*)Vt;
    char* const Pw  = (char*)&Ps[w][0];

    // ---- Q fragments (registers, one-time) ----
    short8 qf[2];
    {
        const int qrow = qb + w * 16 + (lane & 15);
        const float* qp = q + (size_t)(b * N_ + qrow) * 1024 + h * 64 + ((lane >> 4) * 8);
        #pragma unroll
        for (int ks = 0; ks < 2; ++ks) {
            const float4 a = *reinterpret_cast<const float4*>(qp + ks * 32);
            const float4 c = *reinterpret_cast<const float4*>(qp + ks * 32 + 4);
            qf[ks] = pack8(a, c);
        }
    }

    float m[4] = {-1e30f, -1e30f, -1e30f, -1e30f};
    float l[4] = {0.f, 0.f, 0.f, 0.f};
    f32x4 oacc[4] = {};  // 4 d-tiles of 16

    const int nt = blockIdx.x + 1;
    for (int t = 0; t < nt; ++t) {
        const int jb = t * 64;
        __syncthreads();  // previous tile's reads done before restage

        // ---- stage K (row-major, swizzled) + V (transposed, swizzled) ----
        #pragma unroll
        for (int i = 0; i < 2; ++i) {
            {
                const int kkey = (i * 256 + tid) >> 3;
                const int kd0 = (tid & 7) * 8;
                const float* kp = kv + (size_t)(b * N_ + jb + kkey) * 2048 + h * 64 + kd0;
                const float4 a = *reinterpret_cast<const float4*>(kp);
                const float4 c = *reinterpret_cast<const float4*>(kp + 4);
                const int addr = (kkey * 128 + kd0 * 2) ^ ((kkey & 7) << 4);
                *reinterpret_cast<short8*>(Ksc + addr) = pack8(a, c);
            }
            {
                const int vkey = i * 32 + (tid & 31);
                const int vd0 = (tid >> 5) * 8;
                const float* vp = kv + (size_t)(b * N_ + jb + vkey) * 2048 + 1024 + h * 64 + vd0;
                const float4 a = *reinterpret_cast<const float4*>(vp);
                const float4 c = *reinterpret_cast<const float4*>(vp + 4);
                float vv[8] = {a.x, a.y, a.z, a.w, c.x, c.y, c.z, c.w};
                #pragma unroll
                for (int j = 0; j < 8; ++j) {
                    const int addr = ((vd0 + j) * 128 + vkey * 2) ^ (j << 4);
                    *reinterpret_cast<unsigned short*>(Vtc + addr) = f2bf(vv[j]);
                }
            }
        }
        __syncthreads();

        // ---- QK^T: 4 column tiles of 16 keys ----
        f32x4 st[4];
        #pragma unroll
        for (int ct = 0; ct < 4; ++ct) {
            f32x4 acc = {0.f, 0.f, 0.f, 0.f};
            #pragma unroll
            for (int ks = 0; ks < 2; ++ks) {
                const int key = ct * 16 + (lane & 15);
                const int addr = (key * 128 + ks * 64 + ((lane >> 4) * 16)) ^ ((key & 7) << 4);
                const short8 kf = *reinterpret_cast<const short8*>(Ksc + addr);
                acc = __builtin_amdgcn_mfma_f32_16x16x32_bf16(qf[ks], kf, acc, 0, 0, 0);
            }
            st[ct] = acc;
        }

        // ---- online softmax (f32) ----
        const bool diag = (t == nt - 1);
        #pragma unroll
        for (int r = 0; r < 4; ++r) {
            const int qrow = qb + w * 16 + ((lane >> 4) * 4) + r;
            float mx = -1e30f;
            if (diag) {
                #pragma unroll
                for (int ct = 0; ct < 4; ++ct) {
                    const int key = jb + ct * 16 + (lane & 15);
                    const float sv = (key <= qrow) ? st[ct][r] : -1e30f;
                    st[ct][r] = sv;
                    mx = fmaxf(mx, sv);
                }
            } else {
                #pragma unroll
                for (int ct = 0; ct < 4; ++ct) mx = fmaxf(mx, st[ct][r]);
            }
            #pragma unroll
            for (int off = 8; off; off >>= 1) mx = fmaxf(mx, __shfl_xor(mx, off, 64));
            const float mn = fmaxf(m[r], mx);
            const float corr = __expf(m[r] - mn);
            float rs = 0.f;
            #pragma unroll
            for (int ct = 0; ct < 4; ++ct) {
                const float p = __expf(st[ct][r] - mn);
                st[ct][r] = p;
                rs += p;
            }
            #pragma unroll
            for (int off = 8; off; off >>= 1) rs += __shfl_xor(rs, off, 64);
            l[r] = l[r] * corr + rs;
            m[r] = mn;
            #pragma unroll
            for (int dt = 0; dt < 4; ++dt) oacc[dt][r] *= corr;
        }

        // ---- P -> LDS (bf16, swizzled [row][key]) ----
        #pragma unroll
        for (int r = 0; r < 4; ++r) {
            const int prow = ((lane >> 4) * 4) + r;
            #pragma unroll
            for (int ct = 0; ct < 4; ++ct) {
                const int pcol = ct * 16 + (lane & 15);
                const int addr = (prow * 128 + pcol * 2) ^ ((prow & 7) << 4);
                *reinterpret_cast<unsigned short*>(Pw + addr) = f2bf(st[ct][r]);
            }
        }

        // ---- PV: O += P @ V ----
        #pragma unroll
        for (int dt = 0; dt < 4; ++dt) {
            f32x4 acc = oacc[dt];
            #pragma unroll
            for (int ks = 0; ks < 2; ++ks) {
                const int prow = lane & 15;
                const int paddr = (prow * 128 + ks * 64 + ((lane >> 4) * 16)) ^ ((prow & 7) << 4);
                const short8 pf = *reinterpret_cast<const short8*>(Pw + paddr);
                const int vd = dt * 16 + (lane & 15);
                const int vaddr = (vd * 128 + ks * 64 + ((lane >> 4) * 16)) ^ ((vd & 7) << 4);
                const short8 vf = *reinterpret_cast<const short8*>(Vtc + vaddr);
                acc = __builtin_amdgcn_mfma_f32_16x16x32_bf16(pf, vf, acc, 0, 0, 0);
            }
            oacc[dt] = acc;
        }
    }

    // ---- epilogue ----
    #pragma unroll
    for (int r = 0; r < 4; ++r) {
        const int qrow = qb + w * 16 + ((lane >> 4) * 4) + r;
        const float inv = 1.0f / l[r];
        #pragma unroll
        for (int dt = 0; dt < 4; ++dt) {
            att[(size_t)(b * N_ + qrow) * 1024 + h * 64 + dt * 16 + (lane & 15)] = oacc[dt][r] * inv;
        }
    }
}

extern "C" void kernel_launch(void* const* d_in, const int* in_sizes, int n_in,
                              void* d_out, int out_size, void* d_ws, size_t ws_size,
                              hipStream_t stream) {
    const float* x     = (const float*)d_in[0];
    const float* pos   = (const float*)d_in[1];
    const float* gamma = (const float*)d_in[2];
    const float* Wq    = (const float*)d_in[3];
    const float* Wkv   = (const float*)d_in[4];
    const float* Wo    = (const float*)d_in[5];
    const float* bo    = (const float*)d_in[6];
    float* out = (float*)d_out;
    float* ws  = (float*)d_ws;

    float* xn  = ws;                             // 4M floats; reused as attention output
    float* q   = ws + (size_t)4 * 1024 * 1024;   // 4M floats
    float* kv  = ws + (size_t)8 * 1024 * 1024;   // 8M floats
    float* att = xn;

    const int ROWS = B_ * N_;  // 4096

    rmsnorm_kernel<<<ROWS, 256, 0, stream>>>(x, gamma, xn);

    gemm_kernel<false><<<dim3(1024 / 64, ROWS / 64), 256, 0, stream>>>(
        xn, Wq, nullptr, q, ROWS, 1024, 1024);
    gemm_kernel<false><<<dim3(2048 / 64, ROWS / 64), 256, 0, stream>>>(
        x, Wkv, nullptr, kv, ROWS, 2048, 1024);

    rope_kernel<<<(B_ * N_ * H_ * 32) / 256, 256, 0, stream>>>(q, pos, 1024, 0.125f);
    rope_kernel<<<(B_ * N_ * H_ * 32) / 256, 256, 0, stream>>>(kv, pos, 2048, 1.0f);

    attn_mfma_kernel<<<dim3(N_ / 64, B_ * H_), 256, 0, stream>>>(q, kv, att);

    gemm_kernel<true><<<dim3(1024 / 64, ROWS / 64), 256, 0, stream>>>(
        att, Wo, bo, out, ROWS, 1024, 1024);
}

// Round 3
// 239.742 us; speedup vs baseline: 6.2271x; 3.0480x over previous
//
#include <hip/hip_runtime.h>
#include <cmath>

#define B_ 2
#define N_ 2048
#define D_ 1024
#define H_ 16

typedef __attribute__((ext_vector_type(8))) short short8;
typedef __attribute__((ext_vector_type(4))) float f32x4;
typedef __attribute__((ext_vector_type(4))) unsigned short u16x4;

__device__ __forceinline__ unsigned short f2bf(float f) {
    union { float f; unsigned u; } x;
    x.f = f;
    unsigned r = x.u + 0x7FFFu + ((x.u >> 16) & 1u);
    return (unsigned short)(r >> 16);
}
__device__ __forceinline__ float bf2f(unsigned short u) {
    union { unsigned u; float f; } x;
    x.u = ((unsigned)u) << 16;
    return x.f;
}
__device__ __forceinline__ void gload_lds16(const void* g, void* l) {
    __builtin_amdgcn_global_load_lds((const __attribute__((address_space(1))) unsigned*)g,
                                     (__attribute__((address_space(3))) unsigned*)l,
                                     16, 0, 0);
}

// ---------------- RMS-like norm -> bf16 xn, plus bf16 copy of x ----------------
__global__ __launch_bounds__(256) void rmsnorm_kernel(const float* __restrict__ x,
                                                      const float* __restrict__ gamma,
                                                      unsigned short* __restrict__ xn,
                                                      unsigned short* __restrict__ xb) {
    const int row = blockIdx.x;
    const float4 v = reinterpret_cast<const float4*>(x + (size_t)row * D_)[threadIdx.x];
    float ss = v.x * v.x + v.y * v.y + v.z * v.z + v.w * v.w;
    #pragma unroll
    for (int off = 32; off; off >>= 1) ss += __shfl_xor(ss, off, 64);
    __shared__ float wss[4];
    if ((threadIdx.x & 63) == 0) wss[threadIdx.x >> 6] = ss;
    __syncthreads();
    const float tot = wss[0] + wss[1] + wss[2] + wss[3];
    const float inv = 1.0f / fmaxf(sqrtf(tot * (1.0f / D_)), 1e-8f);
    const float4 g = reinterpret_cast<const float4*>(gamma)[threadIdx.x];
    u16x4 on, ox;
    on[0] = f2bf(v.x * inv * g.x); on[1] = f2bf(v.y * inv * g.y);
    on[2] = f2bf(v.z * inv * g.z); on[3] = f2bf(v.w * inv * g.w);
    ox[0] = f2bf(v.x); ox[1] = f2bf(v.y); ox[2] = f2bf(v.z); ox[3] = f2bf(v.w);
    *reinterpret_cast<u16x4*>(xn + (size_t)row * D_ + threadIdx.x * 4) = on;
    *reinterpret_cast<u16x4*>(xb + (size_t)row * D_ + threadIdx.x * 4) = ox;
}

// ---------------- W (f32, [K][Nm]) -> W^T (bf16, [Nm][K]) ----------------
__global__ __launch_bounds__(256) void convT_kernel(const float* __restrict__ W,
                                                    unsigned short* __restrict__ Wt,
                                                    int Nm, int K) {
    __shared__ float tile[32][33];
    const int n0 = blockIdx.x * 32, k0 = blockIdx.y * 32;
    const int r = threadIdx.x >> 3, c4 = (threadIdx.x & 7) * 4;
    const float4 ld = *reinterpret_cast<const float4*>(W + (size_t)(k0 + r) * Nm + n0 + c4);
    tile[r][c4 + 0] = ld.x; tile[r][c4 + 1] = ld.y;
    tile[r][c4 + 2] = ld.z; tile[r][c4 + 3] = ld.w;
    __syncthreads();
    u16x4 o;
    #pragma unroll
    for (int j = 0; j < 4; ++j) o[j] = f2bf(tile[c4 + j][r]);
    *reinterpret_cast<u16x4*>(Wt + (size_t)(n0 + r) * K + k0 + c4) = o;
}

// ---------------- bf16 MFMA GEMM: C = A(MxK) @ Bt^T, Bt is (Nmat x K) ----------------
// BM=128, BK=64, 256 threads (4 waves, 2x2), wave tile 64 x BN/2.
template <int BN, bool BIAS, bool OUTBF>
__global__ __launch_bounds__(256) void gemm_bf16(const unsigned short* __restrict__ A,
                                                 const unsigned short* __restrict__ Bt,
                                                 const float* __restrict__ bias,
                                                 void* __restrict__ Cout,
                                                 int M, int Nmat, int K) {
    constexpr int WN = BN / 2;
    constexpr int NF = BN / 32;
    __shared__ unsigned short As[128 * 64];
    __shared__ unsigned short Bs[BN * 64];
    const int tid = threadIdx.x, lane = tid & 63, w = tid >> 6;
    const int m0 = blockIdx.y * 128, n0 = blockIdx.x * BN;
    const int wm = w >> 1, wn = w & 1;

    const int sr = tid >> 3;              // staging row step
    const int sc = (tid & 7) * 8;         // staging col (elements)

    f32x4 acc[4][NF] = {};

    for (int k0 = 0; k0 < K; k0 += 64) {
        __syncthreads();
        #pragma unroll
        for (int i = 0; i < 4; ++i) {
            const int r = i * 32 + sr;
            const unsigned short* src = A + (size_t)(m0 + r) * K + k0 + (sc ^ ((r & 7) << 3));
            gload_lds16(src, (char*)As + i * 4096 + w * 1024);
        }
        #pragma unroll
        for (int i = 0; i < NF; ++i) {
            const int r = i * 32 + sr;
            const unsigned short* src = Bt + (size_t)(n0 + r) * K + k0 + (sc ^ ((r & 7) << 3));
            gload_lds16(src, (char*)Bs + i * 4096 + w * 1024);
        }
        __syncthreads();

        short8 af[4][2], bf[NF][2];
        #pragma unroll
        for (int mf = 0; mf < 4; ++mf)
            #pragma unroll
            for (int ks = 0; ks < 2; ++ks) {
                const int r = wm * 64 + mf * 16 + (lane & 15);
                const int cb = (ks * 64 + ((lane >> 4) * 16)) ^ ((r & 7) << 4);
                af[mf][ks] = *reinterpret_cast<const short8*>((const char*)As + r * 128 + cb);
            }
        #pragma unroll
        for (int nf = 0; nf < NF; ++nf)
            #pragma unroll
            for (int ks = 0; ks < 2; ++ks) {
                const int r = wn * WN + nf * 16 + (lane & 15);
                const int cb = (ks * 64 + ((lane >> 4) * 16)) ^ ((r & 7) << 4);
                bf[nf][ks] = *reinterpret_cast<const short8*>((const char*)Bs + r * 128 + cb);
            }
        #pragma unroll
        for (int ks = 0; ks < 2; ++ks)
            #pragma unroll
            for (int mf = 0; mf < 4; ++mf)
                #pragma unroll
                for (int nf = 0; nf < NF; ++nf)
                    acc[mf][nf] = __builtin_amdgcn_mfma_f32_16x16x32_bf16(af[mf][ks], bf[nf][ks], acc[mf][nf], 0, 0, 0);
    }

    float bb[NF];
    #pragma unroll
    for (int nf = 0; nf < NF; ++nf)
        bb[nf] = BIAS ? bias[n0 + wn * WN + nf * 16 + (lane & 15)] : 0.0f;

    #pragma unroll
    for (int mf = 0; mf < 4; ++mf)
        #pragma unroll
        for (int nf = 0; nf < NF; ++nf)
            #pragma unroll
            for (int reg = 0; reg < 4; ++reg) {
                const int row = m0 + wm * 64 + mf * 16 + (lane >> 4) * 4 + reg;
                const int col = n0 + wn * WN + nf * 16 + (lane & 15);
                const float val = acc[mf][nf][reg] + bb[nf];
                if (OUTBF)
                    ((unsigned short*)Cout)[(size_t)row * Nmat + col] = f2bf(val);
                else
                    ((float*)Cout)[(size_t)row * Nmat + col] = val;
            }
}

// ---------------- in-place RoPE on bf16, 4 dims per thread ----------------
__global__ __launch_bounds__(256) void rope_bf16_kernel(unsigned short* __restrict__ t,
                                                        const float* __restrict__ pos,
                                                        int row_len, float scale) {
    const int idx = blockIdx.x * 256 + threadIdx.x;  // B*N*H*8 total
    const int d4 = (idx & 7) * 4;
    const int h = (idx >> 3) & 15;
    const int n = (idx >> 7) & (N_ - 1);
    const int b = idx >> 18;
    const size_t base = (size_t)(b * N_ + n) * row_len + h * 64;
    u16x4 u1 = *reinterpret_cast<u16x4*>(t + base + d4);
    u16x4 u2 = *reinterpret_cast<u16x4*>(t + base + 32 + d4);
    const float4 f1 = *reinterpret_cast<const float4*>(pos + n * 64 + d4);
    const float4 f2 = *reinterpret_cast<const float4*>(pos + n * 64 + 32 + d4);
    const float f1a[4] = {f1.x, f1.y, f1.z, f1.w};
    const float f2a[4] = {f2.x, f2.y, f2.z, f2.w};
    #pragma unroll
    for (int j = 0; j < 4; ++j) {
        const float x1 = bf2f(u1[j]), x2 = bf2f(u2[j]);
        u1[j] = f2bf(scale * (x1 * cosf(f1a[j]) - x2 * sinf(f1a[j])));
        u2[j] = f2bf(scale * (x2 * cosf(f2a[j]) + x1 * sinf(f2a[j])));
    }
    *reinterpret_cast<u16x4*>(t + base + d4) = u1;
    *reinterpret_cast<u16x4*>(t + base + 32 + d4) = u2;
}

// ---------------- bf16 MFMA causal flash attention ----------------
__global__ __launch_bounds__(256) void attn_mfma_kernel(const unsigned short* __restrict__ q,
                                                        const unsigned short* __restrict__ kv,
                                                        unsigned short* __restrict__ att) {
    const int bh = blockIdx.y;
    const int b = bh >> 4, h = bh & 15;
    const int qb = blockIdx.x * 64;
    const int tid = threadIdx.x;
    const int lane = tid & 63;
    const int w = tid >> 6;

    __shared__ __align__(16) unsigned short Ks[64 * 64];       // [key][d] swizzled
    __shared__ __align__(16) unsigned short Vt[64 * 64];       // [d][key] swizzled
    __shared__ __align__(16) unsigned short Ps[4][16 * 64];
    char* const Ksc = (char*)Ks;
    char* const Vtc = (char*)Vt;
    char* const Pw  = (char*)&Ps[w][0];

    short8 qf[2];
    {
        const int qrow = qb + w * 16 + (lane & 15);
        const unsigned short* qp = q + (size_t)(b * N_ + qrow) * 1024 + h * 64 + ((lane >> 4) * 8);
        qf[0] = *reinterpret_cast<const short8*>(qp);
        qf[1] = *reinterpret_cast<const short8*>(qp + 32);
    }

    float m[4] = {-1e30f, -1e30f, -1e30f, -1e30f};
    float l[4] = {0.f, 0.f, 0.f, 0.f};
    f32x4 oacc[4] = {};

    const int nt = blockIdx.x + 1;
    for (int t = 0; t < nt; ++t) {
        const int jb = t * 64;
        __syncthreads();

        // K: global_load_lds straight into swizzled layout (pre-swizzled source)
        #pragma unroll
        for (int i = 0; i < 2; ++i) {
            const int r = i * 32 + (tid >> 3);
            const int c = (tid & 7) * 8;
            const unsigned short* src = kv + (size_t)(b * N_ + jb + r) * 2048 + h * 64 + (c ^ ((r & 7) << 3));
            gload_lds16(src, Ksc + i * 4096 + w * 1024);
        }
        // V: register-staged transpose into [d][key]
        #pragma unroll
        for (int i = 0; i < 2; ++i) {
            const int vkey = i * 32 + (tid & 31);
            const int vd0 = (tid >> 5) * 8;
            const short8 vv = *reinterpret_cast<const short8*>(
                kv + (size_t)(b * N_ + jb + vkey) * 2048 + 1024 + h * 64 + vd0);
            #pragma unroll
            for (int j = 0; j < 8; ++j) {
                const int addr = ((vd0 + j) * 128 + vkey * 2) ^ (j << 4);
                *reinterpret_cast<unsigned short*>(Vtc + addr) = (unsigned short)vv[j];
            }
        }
        __syncthreads();

        // QK^T
        f32x4 st[4];
        #pragma unroll
        for (int ct = 0; ct < 4; ++ct) {
            f32x4 acc = {0.f, 0.f, 0.f, 0.f};
            #pragma unroll
            for (int ks = 0; ks < 2; ++ks) {
                const int key = ct * 16 + (lane & 15);
                const int addr = (key * 128 + ks * 64 + ((lane >> 4) * 16)) ^ ((key & 7) << 4);
                const short8 kf = *reinterpret_cast<const short8*>(Ksc + addr);
                acc = __builtin_amdgcn_mfma_f32_16x16x32_bf16(qf[ks], kf, acc, 0, 0, 0);
            }
            st[ct] = acc;
        }

        // online softmax
        const bool diag = (t == nt - 1);
        #pragma unroll
        for (int r = 0; r < 4; ++r) {
            const int qrow = qb + w * 16 + ((lane >> 4) * 4) + r;
            float mx = -1e30f;
            if (diag) {
                #pragma unroll
                for (int ct = 0; ct < 4; ++ct) {
                    const int key = jb + ct * 16 + (lane & 15);
                    const float sv = (key <= qrow) ? st[ct][r] : -1e30f;
                    st[ct][r] = sv;
                    mx = fmaxf(mx, sv);
                }
            } else {
                #pragma unroll
                for (int ct = 0; ct < 4; ++ct) mx = fmaxf(mx, st[ct][r]);
            }
            #pragma unroll
            for (int off = 8; off; off >>= 1) mx = fmaxf(mx, __shfl_xor(mx, off, 64));
            const float mn = fmaxf(m[r], mx);
            const float corr = __expf(m[r] - mn);
            float rs = 0.f;
            #pragma unroll
            for (int ct = 0; ct < 4; ++ct) {
                const float p = __expf(st[ct][r] - mn);
                st[ct][r] = p;
                rs += p;
            }
            #pragma unroll
            for (int off = 8; off; off >>= 1) rs += __shfl_xor(rs, off, 64);
            l[r] = l[r] * corr + rs;
            m[r] = mn;
            #pragma unroll
            for (int dt = 0; dt < 4; ++dt) oacc[dt][r] *= corr;
        }

        // P -> LDS (bf16, swizzled)
        #pragma unroll
        for (int r = 0; r < 4; ++r) {
            const int prow = ((lane >> 4) * 4) + r;
            #pragma unroll
            for (int ct = 0; ct < 4; ++ct) {
                const int pcol = ct * 16 + (lane & 15);
                const int addr = (prow * 128 + pcol * 2) ^ ((prow & 7) << 4);
                *reinterpret_cast<unsigned short*>(Pw + addr) = f2bf(st[ct][r]);
            }
        }

        // PV
        #pragma unroll
        for (int dt = 0; dt < 4; ++dt) {
            f32x4 acc = oacc[dt];
            #pragma unroll
            for (int ks = 0; ks < 2; ++ks) {
                const int prow = lane & 15;
                const int paddr = (prow * 128 + ks * 64 + ((lane >> 4) * 16)) ^ ((prow & 7) << 4);
                const short8 pf = *reinterpret_cast<const short8*>(Pw + paddr);
                const int vd = dt * 16 + (lane & 15);
                const int vaddr = (vd * 128 + ks * 64 + ((lane >> 4) * 16)) ^ ((vd & 7) << 4);
                const short8 vf = *reinterpret_cast<const short8*>(Vtc + vaddr);
                acc = __builtin_amdgcn_mfma_f32_16x16x32_bf16(pf, vf, acc, 0, 0, 0);
            }
            oacc[dt] = acc;
        }
    }

    #pragma unroll
    for (int r = 0; r < 4; ++r) {
        const int qrow = qb + w * 16 + ((lane >> 4) * 4) + r;
        const float inv = 1.0f / l[r];
        #pragma unroll
        for (int dt = 0; dt < 4; ++dt) {
            att[(size_t)(b * N_ + qrow) * 1024 + h * 64 + dt * 16 + (lane & 15)] =
                f2bf(oacc[dt][r] * inv);
        }
    }
}

extern "C" void kernel_launch(void* const* d_in, const int* in_sizes, int n_in,
                              void* d_out, int out_size, void* d_ws, size_t ws_size,
                              hipStream_t stream) {
    const float* x     = (const float*)d_in[0];
    const float* pos   = (const float*)d_in[1];
    const float* gamma = (const float*)d_in[2];
    const float* Wq    = (const float*)d_in[3];
    const float* Wkv   = (const float*)d_in[4];
    const float* Wo    = (const float*)d_in[5];
    const float* bo    = (const float*)d_in[6];
    float* out = (float*)d_out;
    char* ws = (char*)d_ws;

    const size_t MB = 1024 * 1024;
    unsigned short* kvb  = (unsigned short*)(ws);             // 16 MB
    unsigned short* qb   = (unsigned short*)(ws + 16 * MB);   // 8 MB
    unsigned short* xn_b = (unsigned short*)(ws + 24 * MB);   // 8 MB (reused as att)
    unsigned short* xb   = (unsigned short*)(ws + 32 * MB);   // 8 MB
    unsigned short* Wqt  = (unsigned short*)(ws + 40 * MB);   // 2 MB
    unsigned short* Wkvt = (unsigned short*)(ws + 42 * MB);   // 4 MB
    unsigned short* Wot  = (unsigned short*)(ws + 46 * MB);   // 2 MB
    unsigned short* att  = xn_b;

    convT_kernel<<<dim3(32, 32), 256, 0, stream>>>(Wq, Wqt, 1024, 1024);
    convT_kernel<<<dim3(64, 32), 256, 0, stream>>>(Wkv, Wkvt, 2048, 1024);
    convT_kernel<<<dim3(32, 32), 256, 0, stream>>>(Wo, Wot, 1024, 1024);

    rmsnorm_kernel<<<B_ * N_, 256, 0, stream>>>(x, gamma, xn_b, xb);

    gemm_bf16<64, false, true><<<dim3(16, 32), 256, 0, stream>>>(
        xn_b, Wqt, nullptr, qb, 4096, 1024, 1024);
    gemm_bf16<128, false, true><<<dim3(16, 32), 256, 0, stream>>>(
        xb, Wkvt, nullptr, kvb, 4096, 2048, 1024);

    rope_bf16_kernel<<<2048, 256, 0, stream>>>(qb, pos, 1024, 0.125f);
    rope_bf16_kernel<<<2048, 256, 0, stream>>>(kvb, pos, 2048, 1.0f);

    attn_mfma_kernel<<<dim3(N_ / 64, B_ * H_), 256, 0, stream>>>(qb, kvb, att);

    gemm_bf16<64, true, false><<<dim3(16, 32), 256, 0, stream>>>(
        att, Wot, bo, out, 4096, 1024, 1024);
}

// Round 4
// 237.875 us; speedup vs baseline: 6.2759x; 1.0078x over previous
//
#include <hip/hip_runtime.h>
#include <cmath>

#define B_ 2
#define N_ 2048
#define D_ 1024
#define H_ 16

typedef __attribute__((ext_vector_type(8))) short short8;
typedef __attribute__((ext_vector_type(4))) float f32x4;
typedef __attribute__((ext_vector_type(4))) unsigned short u16x4;

__device__ __forceinline__ unsigned short f2bf(float f) {
    union { float f; unsigned u; } x;
    x.f = f;
    unsigned r = x.u + 0x7FFFu + ((x.u >> 16) & 1u);
    return (unsigned short)(r >> 16);
}
__device__ __forceinline__ float bf2f(unsigned short u) {
    union { unsigned u; float f; } x;
    x.u = ((unsigned)u) << 16;
    return x.f;
}
__device__ __forceinline__ void gload_lds16(const void* g, void* l) {
    __builtin_amdgcn_global_load_lds((const __attribute__((address_space(1))) unsigned*)g,
                                     (__attribute__((address_space(3))) unsigned*)l,
                                     16, 0, 0);
}

// ---------------- RMS-like norm -> bf16 xn, plus bf16 copy of x ----------------
__global__ __launch_bounds__(256) void rmsnorm_kernel(const float* __restrict__ x,
                                                      const float* __restrict__ gamma,
                                                      unsigned short* __restrict__ xn,
                                                      unsigned short* __restrict__ xb) {
    const int row = blockIdx.x;
    const float4 v = reinterpret_cast<const float4*>(x + (size_t)row * D_)[threadIdx.x];
    float ss = v.x * v.x + v.y * v.y + v.z * v.z + v.w * v.w;
    #pragma unroll
    for (int off = 32; off; off >>= 1) ss += __shfl_xor(ss, off, 64);
    __shared__ float wss[4];
    if ((threadIdx.x & 63) == 0) wss[threadIdx.x >> 6] = ss;
    __syncthreads();
    const float tot = wss[0] + wss[1] + wss[2] + wss[3];
    const float inv = 1.0f / fmaxf(sqrtf(tot * (1.0f / D_)), 1e-8f);
    const float4 g = reinterpret_cast<const float4*>(gamma)[threadIdx.x];
    u16x4 on, ox;
    on[0] = f2bf(v.x * inv * g.x); on[1] = f2bf(v.y * inv * g.y);
    on[2] = f2bf(v.z * inv * g.z); on[3] = f2bf(v.w * inv * g.w);
    ox[0] = f2bf(v.x); ox[1] = f2bf(v.y); ox[2] = f2bf(v.z); ox[3] = f2bf(v.w);
    *reinterpret_cast<u16x4*>(xn + (size_t)row * D_ + threadIdx.x * 4) = on;
    *reinterpret_cast<u16x4*>(xb + (size_t)row * D_ + threadIdx.x * 4) = ox;
}

// ---------------- W (f32, [K][Nm]) -> W^T (bf16, [Nm][K]) ----------------
__global__ __launch_bounds__(256) void convT_kernel(const float* __restrict__ W,
                                                    unsigned short* __restrict__ Wt,
                                                    int Nm, int K) {
    __shared__ float tile[32][33];
    const int n0 = blockIdx.x * 32, k0 = blockIdx.y * 32;
    const int r = threadIdx.x >> 3, c4 = (threadIdx.x & 7) * 4;
    const float4 ld = *reinterpret_cast<const float4*>(W + (size_t)(k0 + r) * Nm + n0 + c4);
    tile[r][c4 + 0] = ld.x; tile[r][c4 + 1] = ld.y;
    tile[r][c4 + 2] = ld.z; tile[r][c4 + 3] = ld.w;
    __syncthreads();
    u16x4 o;
    #pragma unroll
    for (int j = 0; j < 4; ++j) o[j] = f2bf(tile[c4 + j][r]);
    *reinterpret_cast<u16x4*>(Wt + (size_t)(n0 + r) * K + k0 + c4) = o;
}

// ---------------- V half of kv -> Vt[bh][d][n] (bf16) ----------------
__global__ __launch_bounds__(256) void transposeV_kernel(const unsigned short* __restrict__ kv,
                                                         unsigned short* __restrict__ vt) {
    __shared__ unsigned short tile[64][72];
    const int bh = blockIdx.y;
    const int b = bh >> 4, h = bh & 15;
    const int n0 = blockIdx.x * 64;
    const int tid = threadIdx.x;
    const int r = tid >> 3, c = (tid & 7) * 8;
    #pragma unroll
    for (int i = 0; i < 2; ++i) {
        const int n = i * 32 + r;
        const short8 v = *reinterpret_cast<const short8*>(
            kv + (size_t)(b * N_ + n0 + n) * 2048 + 1024 + h * 64 + c);
        *reinterpret_cast<short8*>(&tile[n][c]) = v;
    }
    __syncthreads();
    #pragma unroll
    for (int i = 0; i < 2; ++i) {
        const int d = i * 32 + r;
        short8 o;
        #pragma unroll
        for (int j = 0; j < 8; ++j) o[j] = (short)tile[c + j][d];
        *reinterpret_cast<short8*>(vt + ((size_t)bh * 64 + d) * 2048 + n0 + c) = o;
    }
}

// ---------------- bf16 MFMA GEMM (unchanged from R3) ----------------
template <int BN, bool BIAS, bool OUTBF>
__global__ __launch_bounds__(256) void gemm_bf16(const unsigned short* __restrict__ A,
                                                 const unsigned short* __restrict__ Bt,
                                                 const float* __restrict__ bias,
                                                 void* __restrict__ Cout,
                                                 int M, int Nmat, int K) {
    constexpr int WN = BN / 2;
    constexpr int NF = BN / 32;
    __shared__ unsigned short As[128 * 64];
    __shared__ unsigned short Bs[BN * 64];
    const int tid = threadIdx.x, lane = tid & 63, w = tid >> 6;
    const int m0 = blockIdx.y * 128, n0 = blockIdx.x * BN;
    const int wm = w >> 1, wn = w & 1;

    const int sr = tid >> 3;
    const int sc = (tid & 7) * 8;

    f32x4 acc[4][NF] = {};

    for (int k0 = 0; k0 < K; k0 += 64) {
        __syncthreads();
        #pragma unroll
        for (int i = 0; i < 4; ++i) {
            const int r = i * 32 + sr;
            const unsigned short* src = A + (size_t)(m0 + r) * K + k0 + (sc ^ ((r & 7) << 3));
            gload_lds16(src, (char*)As + i * 4096 + w * 1024);
        }
        #pragma unroll
        for (int i = 0; i < NF; ++i) {
            const int r = i * 32 + sr;
            const unsigned short* src = Bt + (size_t)(n0 + r) * K + k0 + (sc ^ ((r & 7) << 3));
            gload_lds16(src, (char*)Bs + i * 4096 + w * 1024);
        }
        __syncthreads();

        short8 af[4][2], bf[NF][2];
        #pragma unroll
        for (int mf = 0; mf < 4; ++mf)
            #pragma unroll
            for (int ks = 0; ks < 2; ++ks) {
                const int r = wm * 64 + mf * 16 + (lane & 15);
                const int cb = (ks * 64 + ((lane >> 4) * 16)) ^ ((r & 7) << 4);
                af[mf][ks] = *reinterpret_cast<const short8*>((const char*)As + r * 128 + cb);
            }
        #pragma unroll
        for (int nf = 0; nf < NF; ++nf)
            #pragma unroll
            for (int ks = 0; ks < 2; ++ks) {
                const int r = wn * WN + nf * 16 + (lane & 15);
                const int cb = (ks * 64 + ((lane >> 4) * 16)) ^ ((r & 7) << 4);
                bf[nf][ks] = *reinterpret_cast<const short8*>((const char*)Bs + r * 128 + cb);
            }
        #pragma unroll
        for (int ks = 0; ks < 2; ++ks)
            #pragma unroll
            for (int mf = 0; mf < 4; ++mf)
                #pragma unroll
                for (int nf = 0; nf < NF; ++nf)
                    acc[mf][nf] = __builtin_amdgcn_mfma_f32_16x16x32_bf16(af[mf][ks], bf[nf][ks], acc[mf][nf], 0, 0, 0);
    }

    float bb[NF];
    #pragma unroll
    for (int nf = 0; nf < NF; ++nf)
        bb[nf] = BIAS ? bias[n0 + wn * WN + nf * 16 + (lane & 15)] : 0.0f;

    #pragma unroll
    for (int mf = 0; mf < 4; ++mf)
        #pragma unroll
        for (int nf = 0; nf < NF; ++nf)
            #pragma unroll
            for (int reg = 0; reg < 4; ++reg) {
                const int row = m0 + wm * 64 + mf * 16 + (lane >> 4) * 4 + reg;
                const int col = n0 + wn * WN + nf * 16 + (lane & 15);
                const float val = acc[mf][nf][reg] + bb[nf];
                if (OUTBF)
                    ((unsigned short*)Cout)[(size_t)row * Nmat + col] = f2bf(val);
                else
                    ((float*)Cout)[(size_t)row * Nmat + col] = val;
            }
}

// ---------------- in-place RoPE on bf16 ----------------
__global__ __launch_bounds__(256) void rope_bf16_kernel(unsigned short* __restrict__ t,
                                                        const float* __restrict__ pos,
                                                        int row_len, float scale) {
    const int idx = blockIdx.x * 256 + threadIdx.x;
    const int d4 = (idx & 7) * 4;
    const int h = (idx >> 3) & 15;
    const int n = (idx >> 7) & (N_ - 1);
    const int b = idx >> 18;
    const size_t base = (size_t)(b * N_ + n) * row_len + h * 64;
    u16x4 u1 = *reinterpret_cast<u16x4*>(t + base + d4);
    u16x4 u2 = *reinterpret_cast<u16x4*>(t + base + 32 + d4);
    const float4 f1 = *reinterpret_cast<const float4*>(pos + n * 64 + d4);
    const float4 f2 = *reinterpret_cast<const float4*>(pos + n * 64 + 32 + d4);
    const float f1a[4] = {f1.x, f1.y, f1.z, f1.w};
    const float f2a[4] = {f2.x, f2.y, f2.z, f2.w};
    #pragma unroll
    for (int j = 0; j < 4; ++j) {
        const float x1 = bf2f(u1[j]), x2 = bf2f(u2[j]);
        u1[j] = f2bf(scale * (x1 * cosf(f1a[j]) - x2 * sinf(f1a[j])));
        u2[j] = f2bf(scale * (x2 * cosf(f2a[j]) + x1 * sinf(f2a[j])));
    }
    *reinterpret_cast<u16x4*>(t + base + d4) = u1;
    *reinterpret_cast<u16x4*>(t + base + 32 + d4) = u2;
}

// ---------------- bf16 MFMA causal flash attention, double-buffered ----------------
// grid (N/128, B*H), qi reversed; 4 waves, wave owns 32 q rows (2 fragments).
__global__ __launch_bounds__(256) void attn_mfma_kernel(const unsigned short* __restrict__ q,
                                                        const unsigned short* __restrict__ kv,
                                                        const unsigned short* __restrict__ vt,
                                                        unsigned short* __restrict__ att) {
    const int bh = blockIdx.y;
    const int b = bh >> 4, h = bh & 15;
    const int qi = gridDim.x - 1 - blockIdx.x;   // big blocks dispatch first
    const int qb = qi * 128;
    const int tid = threadIdx.x;
    const int lane = tid & 63;
    const int w = tid >> 6;

    __shared__ __align__(16) unsigned short Ks[2][64 * 64];   // [key][d] swizzled
    __shared__ __align__(16) unsigned short Vs[2][64 * 64];   // [d][key] swizzled (from vt)
    __shared__ __align__(16) unsigned short Ps[4][32 * 64];   // per-wave P, swizzled
    char* const Pw = (char*)&Ps[w][0];

    // Q fragments
    short8 qf[2][2];
    #pragma unroll
    for (int qt = 0; qt < 2; ++qt) {
        const int qrow = qb + w * 32 + qt * 16 + (lane & 15);
        const unsigned short* qp = q + (size_t)(b * N_ + qrow) * 1024 + h * 64 + ((lane >> 4) * 8);
        qf[qt][0] = *reinterpret_cast<const short8*>(qp);
        qf[qt][1] = *reinterpret_cast<const short8*>(qp + 32);
    }

    float m[2][4], l[2][4];
    f32x4 oacc[2][4] = {};
    #pragma unroll
    for (int qt = 0; qt < 2; ++qt)
        #pragma unroll
        for (int r = 0; r < 4; ++r) { m[qt][r] = -1e30f; l[qt][r] = 0.f; }

    const int nt = qi * 2 + 2;
    const int sr = tid >> 3, sc = (tid & 7) * 8;

    // ---- prologue: stage tile 0 into buf 0 ----
    {
        #pragma unroll
        for (int i = 0; i < 2; ++i) {
            const int r = i * 32 + sr;
            const int cs = sc ^ ((r & 7) << 3);
            gload_lds16(kv + (size_t)(b * N_ + r) * 2048 + h * 64 + cs,
                        (char*)Ks[0] + i * 4096 + w * 1024);
            gload_lds16(vt + ((size_t)bh * 64 + r) * 2048 + cs,
                        (char*)Vs[0] + i * 4096 + w * 1024);
        }
    }

    for (int t = 0; t < nt; ++t) {
        const int jb = t * 64;
        // ---- issue next tile's loads (counted vmcnt pipeline) ----
        {
            const int tn = (t + 1 < nt) ? t + 1 : t;
            const int jn = tn * 64;
            char* kd = (char*)Ks[(t + 1) & 1];
            char* vd = (char*)Vs[(t + 1) & 1];
            #pragma unroll
            for (int i = 0; i < 2; ++i) {
                const int r = i * 32 + sr;
                const int cs = sc ^ ((r & 7) << 3);
                gload_lds16(kv + (size_t)(b * N_ + jn + r) * 2048 + h * 64 + cs,
                            kd + i * 4096 + w * 1024);
                gload_lds16(vt + ((size_t)bh * 64 + r) * 2048 + jn + cs,
                            vd + i * 4096 + w * 1024);
            }
        }
        asm volatile("s_waitcnt vmcnt(4)" ::: "memory");  // this tile's 4 loads done; next 4 in flight
        __builtin_amdgcn_s_barrier();

        const char* Ksc = (const char*)Ks[t & 1];
        const char* Vsc = (const char*)Vs[t & 1];

        if (jb <= qb + w * 32 + 31) {   // wave-uniform: skip fully-masked tiles
            // K fragments
            short8 kf[4][2];
            #pragma unroll
            for (int ct = 0; ct < 4; ++ct)
                #pragma unroll
                for (int ks = 0; ks < 2; ++ks) {
                    const int key = ct * 16 + (lane & 15);
                    const int addr = (key * 128 + ks * 64 + ((lane >> 4) * 16)) ^ ((key & 7) << 4);
                    kf[ct][ks] = *reinterpret_cast<const short8*>(Ksc + addr);
                }
            // QK^T
            f32x4 st[2][4];
            __builtin_amdgcn_s_setprio(1);
            #pragma unroll
            for (int qt = 0; qt < 2; ++qt)
                #pragma unroll
                for (int ct = 0; ct < 4; ++ct) {
                    f32x4 acc = {0.f, 0.f, 0.f, 0.f};
                    acc = __builtin_amdgcn_mfma_f32_16x16x32_bf16(qf[qt][0], kf[ct][0], acc, 0, 0, 0);
                    acc = __builtin_amdgcn_mfma_f32_16x16x32_bf16(qf[qt][1], kf[ct][1], acc, 0, 0, 0);
                    st[qt][ct] = acc;
                }
            __builtin_amdgcn_s_setprio(0);

            // online softmax
            const bool need_mask = (jb + 63) > (qb + w * 32);
            #pragma unroll
            for (int qt = 0; qt < 2; ++qt)
                #pragma unroll
                for (int r = 0; r < 4; ++r) {
                    const int qrow = qb + w * 32 + qt * 16 + ((lane >> 4) * 4) + r;
                    float mx = -1e30f;
                    if (need_mask) {
                        #pragma unroll
                        for (int ct = 0; ct < 4; ++ct) {
                            const int key = jb + ct * 16 + (lane & 15);
                            const float sv = (key <= qrow) ? st[qt][ct][r] : -1e30f;
                            st[qt][ct][r] = sv;
                            mx = fmaxf(mx, sv);
                        }
                    } else {
                        #pragma unroll
                        for (int ct = 0; ct < 4; ++ct) mx = fmaxf(mx, st[qt][ct][r]);
                    }
                    #pragma unroll
                    for (int off = 8; off; off >>= 1) mx = fmaxf(mx, __shfl_xor(mx, off, 64));
                    const float mn = fmaxf(m[qt][r], mx);
                    const float corr = __expf(m[qt][r] - mn);
                    float rs = 0.f;
                    #pragma unroll
                    for (int ct = 0; ct < 4; ++ct) {
                        const float p = __expf(st[qt][ct][r] - mn);
                        st[qt][ct][r] = p;
                        rs += p;
                    }
                    #pragma unroll
                    for (int off = 8; off; off >>= 1) rs += __shfl_xor(rs, off, 64);
                    l[qt][r] = l[qt][r] * corr + rs;
                    m[qt][r] = mn;
                    #pragma unroll
                    for (int dt = 0; dt < 4; ++dt) oacc[qt][dt][r] *= corr;
                }

            // P -> per-wave LDS (bf16, swizzled)
            #pragma unroll
            for (int qt = 0; qt < 2; ++qt)
                #pragma unroll
                for (int r = 0; r < 4; ++r) {
                    const int prow = qt * 16 + ((lane >> 4) * 4) + r;
                    #pragma unroll
                    for (int ct = 0; ct < 4; ++ct) {
                        const int pcol = ct * 16 + (lane & 15);
                        const int addr = (prow * 128 + pcol * 2) ^ ((prow & 7) << 4);
                        *reinterpret_cast<unsigned short*>(Pw + addr) = f2bf(st[qt][ct][r]);
                    }
                }

            // PV
            short8 pf[2][2], vf[4][2];
            #pragma unroll
            for (int qt = 0; qt < 2; ++qt)
                #pragma unroll
                for (int ks = 0; ks < 2; ++ks) {
                    const int prow = qt * 16 + (lane & 15);
                    const int addr = (prow * 128 + ks * 64 + ((lane >> 4) * 16)) ^ ((prow & 7) << 4);
                    pf[qt][ks] = *reinterpret_cast<const short8*>(Pw + addr);
                }
            #pragma unroll
            for (int dt = 0; dt < 4; ++dt)
                #pragma unroll
                for (int ks = 0; ks < 2; ++ks) {
                    const int vd = dt * 16 + (lane & 15);
                    const int addr = (vd * 128 + ks * 64 + ((lane >> 4) * 16)) ^ ((vd & 7) << 4);
                    vf[dt][ks] = *reinterpret_cast<const short8*>(Vsc + addr);
                }
            __builtin_amdgcn_s_setprio(1);
            #pragma unroll
            for (int qt = 0; qt < 2; ++qt)
                #pragma unroll
                for (int dt = 0; dt < 4; ++dt) {
                    oacc[qt][dt] = __builtin_amdgcn_mfma_f32_16x16x32_bf16(pf[qt][0], vf[dt][0], oacc[qt][dt], 0, 0, 0);
                    oacc[qt][dt] = __builtin_amdgcn_mfma_f32_16x16x32_bf16(pf[qt][1], vf[dt][1], oacc[qt][dt], 0, 0, 0);
                }
            __builtin_amdgcn_s_setprio(0);
        }
        __builtin_amdgcn_s_barrier();   // all waves done with buf before overwrite
    }

    // ---- epilogue ----
    #pragma unroll
    for (int qt = 0; qt < 2; ++qt)
        #pragma unroll
        for (int r = 0; r < 4; ++r) {
            const int qrow = qb + w * 32 + qt * 16 + ((lane >> 4) * 4) + r;
            const float inv = 1.0f / l[qt][r];
            #pragma unroll
            for (int dt = 0; dt < 4; ++dt) {
                att[(size_t)(b * N_ + qrow) * 1024 + h * 64 + dt * 16 + (lane & 15)] =
                    f2bf(oacc[qt][dt][r] * inv);
            }
        }
}

extern "C" void kernel_launch(void* const* d_in, const int* in_sizes, int n_in,
                              void* d_out, int out_size, void* d_ws, size_t ws_size,
                              hipStream_t stream) {
    const float* x     = (const float*)d_in[0];
    const float* pos   = (const float*)d_in[1];
    const float* gamma = (const float*)d_in[2];
    const float* Wq    = (const float*)d_in[3];
    const float* Wkv   = (const float*)d_in[4];
    const float* Wo    = (const float*)d_in[5];
    const float* bo    = (const float*)d_in[6];
    float* out = (float*)d_out;
    char* ws = (char*)d_ws;

    const size_t MB = 1024 * 1024;
    unsigned short* kvb  = (unsigned short*)(ws);             // 16 MB
    unsigned short* qb   = (unsigned short*)(ws + 16 * MB);   // 8 MB
    unsigned short* xn_b = (unsigned short*)(ws + 24 * MB);   // 8 MB (reused as att)
    unsigned short* xb   = (unsigned short*)(ws + 32 * MB);   // 8 MB
    unsigned short* Wqt  = (unsigned short*)(ws + 40 * MB);   // 2 MB
    unsigned short* Wkvt = (unsigned short*)(ws + 42 * MB);   // 4 MB
    unsigned short* Wot  = (unsigned short*)(ws + 46 * MB);   // 2 MB
    unsigned short* vt   = (unsigned short*)(ws + 48 * MB);   // 8 MB
    unsigned short* att  = xn_b;

    convT_kernel<<<dim3(32, 32), 256, 0, stream>>>(Wq, Wqt, 1024, 1024);
    convT_kernel<<<dim3(64, 32), 256, 0, stream>>>(Wkv, Wkvt, 2048, 1024);
    convT_kernel<<<dim3(32, 32), 256, 0, stream>>>(Wo, Wot, 1024, 1024);

    rmsnorm_kernel<<<B_ * N_, 256, 0, stream>>>(x, gamma, xn_b, xb);

    gemm_bf16<64, false, true><<<dim3(16, 32), 256, 0, stream>>>(
        xn_b, Wqt, nullptr, qb, 4096, 1024, 1024);
    gemm_bf16<128, false, true><<<dim3(16, 32), 256, 0, stream>>>(
        xb, Wkvt, nullptr, kvb, 4096, 2048, 1024);

    rope_bf16_kernel<<<2048, 256, 0, stream>>>(qb, pos, 1024, 0.125f);
    rope_bf16_kernel<<<2048, 256, 0, stream>>>(kvb, pos, 2048, 1.0f);

    transposeV_kernel<<<dim3(32, 32), 256, 0, stream>>>(kvb, vt);

    attn_mfma_kernel<<<dim3(N_ / 128, B_ * H_), 256, 0, stream>>>(qb, kvb, vt, att);

    gemm_bf16<64, true, false><<<dim3(16, 32), 256, 0, stream>>>(
        att, Wot, bo, out, 4096, 1024, 1024);
}

// Round 5
// 184.710 us; speedup vs baseline: 8.0823x; 1.2878x over previous
//
#include <hip/hip_runtime.h>
#include <cmath>

#define B_ 2
#define N_ 2048
#define D_ 1024
#define H_ 16

typedef __attribute__((ext_vector_type(8))) short short8;
typedef __attribute__((ext_vector_type(4))) float f32x4;
typedef __attribute__((ext_vector_type(4))) unsigned short u16x4;

__device__ __forceinline__ unsigned short f2bf(float f) {
    union { float f; unsigned u; } x;
    x.f = f;
    unsigned r = x.u + 0x7FFFu + ((x.u >> 16) & 1u);
    return (unsigned short)(r >> 16);
}
__device__ __forceinline__ float bf2f(unsigned short u) {
    union { unsigned u; float f; } x;
    x.u = ((unsigned)u) << 16;
    return x.f;
}
__device__ __forceinline__ unsigned cvt_pk_bf16(float lo, float hi) {
    unsigned r;
    asm("v_cvt_pk_bf16_f32 %0, %1, %2" : "=v"(r) : "v"(lo), "v"(hi));
    return r;
}
__device__ __forceinline__ void gload_lds16(const void* g, void* l) {
    __builtin_amdgcn_global_load_lds((const __attribute__((address_space(1))) unsigned*)g,
                                     (__attribute__((address_space(3))) unsigned*)l,
                                     16, 0, 0);
}

// ---------------- RMS-like norm -> bf16 xn, plus bf16 copy of x ----------------
__global__ __launch_bounds__(256) void rmsnorm_kernel(const float* __restrict__ x,
                                                      const float* __restrict__ gamma,
                                                      unsigned short* __restrict__ xn,
                                                      unsigned short* __restrict__ xb) {
    const int row = blockIdx.x;
    const float4 v = reinterpret_cast<const float4*>(x + (size_t)row * D_)[threadIdx.x];
    float ss = v.x * v.x + v.y * v.y + v.z * v.z + v.w * v.w;
    #pragma unroll
    for (int off = 32; off; off >>= 1) ss += __shfl_xor(ss, off, 64);
    __shared__ float wss[4];
    if ((threadIdx.x & 63) == 0) wss[threadIdx.x >> 6] = ss;
    __syncthreads();
    const float tot = wss[0] + wss[1] + wss[2] + wss[3];
    const float inv = 1.0f / fmaxf(sqrtf(tot * (1.0f / D_)), 1e-8f);
    const float4 g = reinterpret_cast<const float4*>(gamma)[threadIdx.x];
    u16x4 on, ox;
    on[0] = f2bf(v.x * inv * g.x); on[1] = f2bf(v.y * inv * g.y);
    on[2] = f2bf(v.z * inv * g.z); on[3] = f2bf(v.w * inv * g.w);
    ox[0] = f2bf(v.x); ox[1] = f2bf(v.y); ox[2] = f2bf(v.z); ox[3] = f2bf(v.w);
    *reinterpret_cast<u16x4*>(xn + (size_t)row * D_ + threadIdx.x * 4) = on;
    *reinterpret_cast<u16x4*>(xb + (size_t)row * D_ + threadIdx.x * 4) = ox;
}

// ---------------- W (f32, [K][Nm]) -> W^T (bf16, [Nm][K]) ----------------
__global__ __launch_bounds__(256) void convT_kernel(const float* __restrict__ W,
                                                    unsigned short* __restrict__ Wt,
                                                    int Nm, int K) {
    __shared__ float tile[32][33];
    const int n0 = blockIdx.x * 32, k0 = blockIdx.y * 32;
    const int r = threadIdx.x >> 3, c4 = (threadIdx.x & 7) * 4;
    const float4 ld = *reinterpret_cast<const float4*>(W + (size_t)(k0 + r) * Nm + n0 + c4);
    tile[r][c4 + 0] = ld.x; tile[r][c4 + 1] = ld.y;
    tile[r][c4 + 2] = ld.z; tile[r][c4 + 3] = ld.w;
    __syncthreads();
    u16x4 o;
    #pragma unroll
    for (int j = 0; j < 4; ++j) o[j] = f2bf(tile[c4 + j][r]);
    *reinterpret_cast<u16x4*>(Wt + (size_t)(n0 + r) * K + k0 + c4) = o;
}

// ---------------- V half of kv -> Vt[bh][d][n] (bf16) ----------------
__global__ __launch_bounds__(256) void transposeV_kernel(const unsigned short* __restrict__ kv,
                                                         unsigned short* __restrict__ vt) {
    __shared__ unsigned short tile[64][72];
    const int bh = blockIdx.y;
    const int b = bh >> 4, h = bh & 15;
    const int n0 = blockIdx.x * 64;
    const int tid = threadIdx.x;
    const int r = tid >> 3, c = (tid & 7) * 8;
    #pragma unroll
    for (int i = 0; i < 2; ++i) {
        const int n = i * 32 + r;
        const short8 v = *reinterpret_cast<const short8*>(
            kv + (size_t)(b * N_ + n0 + n) * 2048 + 1024 + h * 64 + c);
        *reinterpret_cast<short8*>(&tile[n][c]) = v;
    }
    __syncthreads();
    #pragma unroll
    for (int i = 0; i < 2; ++i) {
        const int d = i * 32 + r;
        short8 o;
        #pragma unroll
        for (int j = 0; j < 8; ++j) o[j] = (short)tile[c + j][d];
        *reinterpret_cast<short8*>(vt + ((size_t)bh * 64 + d) * 2048 + n0 + c) = o;
    }
}

// ---------------- bf16 MFMA GEMM (unchanged) ----------------
template <int BN, bool BIAS, bool OUTBF>
__global__ __launch_bounds__(256) void gemm_bf16(const unsigned short* __restrict__ A,
                                                 const unsigned short* __restrict__ Bt,
                                                 const float* __restrict__ bias,
                                                 void* __restrict__ Cout,
                                                 int M, int Nmat, int K) {
    constexpr int WN = BN / 2;
    constexpr int NF = BN / 32;
    __shared__ unsigned short As[128 * 64];
    __shared__ unsigned short Bs[BN * 64];
    const int tid = threadIdx.x, lane = tid & 63, w = tid >> 6;
    const int m0 = blockIdx.y * 128, n0 = blockIdx.x * BN;
    const int wm = w >> 1, wn = w & 1;

    const int sr = tid >> 3;
    const int sc = (tid & 7) * 8;

    f32x4 acc[4][NF] = {};

    for (int k0 = 0; k0 < K; k0 += 64) {
        __syncthreads();
        #pragma unroll
        for (int i = 0; i < 4; ++i) {
            const int r = i * 32 + sr;
            const unsigned short* src = A + (size_t)(m0 + r) * K + k0 + (sc ^ ((r & 7) << 3));
            gload_lds16(src, (char*)As + i * 4096 + w * 1024);
        }
        #pragma unroll
        for (int i = 0; i < NF; ++i) {
            const int r = i * 32 + sr;
            const unsigned short* src = Bt + (size_t)(n0 + r) * K + k0 + (sc ^ ((r & 7) << 3));
            gload_lds16(src, (char*)Bs + i * 4096 + w * 1024);
        }
        __syncthreads();

        short8 af[4][2], bf[NF][2];
        #pragma unroll
        for (int mf = 0; mf < 4; ++mf)
            #pragma unroll
            for (int ks = 0; ks < 2; ++ks) {
                const int r = wm * 64 + mf * 16 + (lane & 15);
                const int cb = (ks * 64 + ((lane >> 4) * 16)) ^ ((r & 7) << 4);
                af[mf][ks] = *reinterpret_cast<const short8*>((const char*)As + r * 128 + cb);
            }
        #pragma unroll
        for (int nf = 0; nf < NF; ++nf)
            #pragma unroll
            for (int ks = 0; ks < 2; ++ks) {
                const int r = wn * WN + nf * 16 + (lane & 15);
                const int cb = (ks * 64 + ((lane >> 4) * 16)) ^ ((r & 7) << 4);
                bf[nf][ks] = *reinterpret_cast<const short8*>((const char*)Bs + r * 128 + cb);
            }
        #pragma unroll
        for (int ks = 0; ks < 2; ++ks)
            #pragma unroll
            for (int mf = 0; mf < 4; ++mf)
                #pragma unroll
                for (int nf = 0; nf < NF; ++nf)
                    acc[mf][nf] = __builtin_amdgcn_mfma_f32_16x16x32_bf16(af[mf][ks], bf[nf][ks], acc[mf][nf], 0, 0, 0);
    }

    float bb[NF];
    #pragma unroll
    for (int nf = 0; nf < NF; ++nf)
        bb[nf] = BIAS ? bias[n0 + wn * WN + nf * 16 + (lane & 15)] : 0.0f;

    #pragma unroll
    for (int mf = 0; mf < 4; ++mf)
        #pragma unroll
        for (int nf = 0; nf < NF; ++nf)
            #pragma unroll
            for (int reg = 0; reg < 4; ++reg) {
                const int row = m0 + wm * 64 + mf * 16 + (lane >> 4) * 4 + reg;
                const int col = n0 + wn * WN + nf * 16 + (lane & 15);
                const float val = acc[mf][nf][reg] + bb[nf];
                if (OUTBF)
                    ((unsigned short*)Cout)[(size_t)row * Nmat + col] = f2bf(val);
                else
                    ((float*)Cout)[(size_t)row * Nmat + col] = val;
            }
}

// ---------------- in-place RoPE on bf16 ----------------
__global__ __launch_bounds__(256) void rope_bf16_kernel(unsigned short* __restrict__ t,
                                                        const float* __restrict__ pos,
                                                        int row_len, float scale) {
    const int idx = blockIdx.x * 256 + threadIdx.x;
    const int d4 = (idx & 7) * 4;
    const int h = (idx >> 3) & 15;
    const int n = (idx >> 7) & (N_ - 1);
    const int b = idx >> 18;
    const size_t base = (size_t)(b * N_ + n) * row_len + h * 64;
    u16x4 u1 = *reinterpret_cast<u16x4*>(t + base + d4);
    u16x4 u2 = *reinterpret_cast<u16x4*>(t + base + 32 + d4);
    const float4 f1 = *reinterpret_cast<const float4*>(pos + n * 64 + d4);
    const float4 f2 = *reinterpret_cast<const float4*>(pos + n * 64 + 32 + d4);
    const float f1a[4] = {f1.x, f1.y, f1.z, f1.w};
    const float f2a[4] = {f2.x, f2.y, f2.z, f2.w};
    #pragma unroll
    for (int j = 0; j < 4; ++j) {
        const float x1 = bf2f(u1[j]), x2 = bf2f(u2[j]);
        u1[j] = f2bf(scale * (x1 * cosf(f1a[j]) - x2 * sinf(f1a[j])));
        u2[j] = f2bf(scale * (x2 * cosf(f2a[j]) + x1 * sinf(f2a[j])));
    }
    *reinterpret_cast<u16x4*>(t + base + d4) = u1;
    *reinterpret_cast<u16x4*>(t + base + 32 + d4) = u2;
}

// ---------------- bf16 MFMA causal flash attention (swapped-operand softmax) ----------------
// grid (N/128, B*H), qi reversed; 4 waves, wave owns 32 q rows (2 qt tiles of 16).
// QK^T computed swapped: S^T = mfma(K,Q): lane holds q-row = lane&15 across its regs,
// key = ct*16 + (lane>>4)*4 + reg. Softmax fully per-lane + 2 shuffles per reduce.
// PV also swapped: O^T = mfma(V^T, P^T): oacc col = q-row, row = d.
__global__ __launch_bounds__(256) void attn_mfma_kernel(const unsigned short* __restrict__ q,
                                                        const unsigned short* __restrict__ kv,
                                                        const unsigned short* __restrict__ vt,
                                                        unsigned short* __restrict__ att) {
    const int bh = blockIdx.y;
    const int b = bh >> 4, h = bh & 15;
    const int qi = gridDim.x - 1 - blockIdx.x;   // big causal blocks dispatch first
    const int qb = qi * 128;
    const int tid = threadIdx.x;
    const int lane = tid & 63;
    const int w = tid >> 6;
    const int c = lane & 15;     // q-row within 16-tile (and d-row for vf)
    const int g = lane >> 4;

    __shared__ __align__(16) unsigned short Ks[2][64 * 64];   // [key][d] swizzled
    __shared__ __align__(16) unsigned short Vs[2][64 * 64];   // [d][key] swizzled
    __shared__ __align__(16) unsigned short Ps[4][1024];      // per-wave P^T staging (2KB)
    char* const PB = (char*)&Ps[w][0];

    // Q fragments (B operand): col=c=qrow, k = ks*32 + g*8 + j
    short8 qf[2][2];
    #pragma unroll
    for (int qt = 0; qt < 2; ++qt) {
        const int qrow = qb + w * 32 + qt * 16 + c;
        const unsigned short* qp = q + (size_t)(b * N_ + qrow) * 1024 + h * 64 + g * 8;
        qf[qt][0] = *reinterpret_cast<const short8*>(qp);
        qf[qt][1] = *reinterpret_cast<const short8*>(qp + 32);
    }

    float m[2] = {-1e30f, -1e30f};
    float l[2] = {0.f, 0.f};
    f32x4 oacc[2][4] = {};   // [qt][dt]: col=c=qrow, row=g*4+reg = d within dt

    const int nt = qi * 2 + 2;
    const int sr = tid >> 3, sc = (tid & 7) * 8;

    // ---- prologue: stage tile 0 into buf 0 ----
    #pragma unroll
    for (int i = 0; i < 2; ++i) {
        const int r = i * 32 + sr;
        const int cs = sc ^ ((r & 7) << 3);
        gload_lds16(kv + (size_t)(b * N_ + r) * 2048 + h * 64 + cs,
                    (char*)Ks[0] + i * 4096 + w * 1024);
        gload_lds16(vt + ((size_t)bh * 64 + r) * 2048 + cs,
                    (char*)Vs[0] + i * 4096 + w * 1024);
    }

    for (int t = 0; t < nt; ++t) {
        const int jb = t * 64;
        // issue next tile's loads (counted-vmcnt pipeline)
        {
            const int tn = (t + 1 < nt) ? t + 1 : t;
            const int jn = tn * 64;
            char* kd = (char*)Ks[(t + 1) & 1];
            char* vd = (char*)Vs[(t + 1) & 1];
            #pragma unroll
            for (int i = 0; i < 2; ++i) {
                const int r = i * 32 + sr;
                const int cs = sc ^ ((r & 7) << 3);
                gload_lds16(kv + (size_t)(b * N_ + jn + r) * 2048 + h * 64 + cs,
                            kd + i * 4096 + w * 1024);
                gload_lds16(vt + ((size_t)bh * 64 + r) * 2048 + jn + cs,
                            vd + i * 4096 + w * 1024);
            }
        }
        asm volatile("s_waitcnt vmcnt(4)" ::: "memory");
        __builtin_amdgcn_s_barrier();

        const char* Ksc = (const char*)Ks[t & 1];
        const char* Vsc = (const char*)Vs[t & 1];

        if (jb <= qb + w * 32 + 31) {   // wave-uniform skip of fully-masked tiles
            // K fragments (A operand): row=c=key, k = ks*32 + g*8 + j
            short8 kf[4][2];
            #pragma unroll
            for (int ct = 0; ct < 4; ++ct)
                #pragma unroll
                for (int ks = 0; ks < 2; ++ks) {
                    const int key = ct * 16 + c;
                    const int addr = (key * 128 + ks * 64 + g * 16) ^ ((key & 7) << 4);
                    kf[ct][ks] = *reinterpret_cast<const short8*>(Ksc + addr);
                }

            #pragma unroll
            for (int qt = 0; qt < 2; ++qt) {
                const int qrow = qb + w * 32 + qt * 16 + c;
                // S^T = K·Q^T : lane holds row=qrow(c), key = jb + ct*16 + g*4 + reg
                f32x4 st[4];
                __builtin_amdgcn_s_setprio(1);
                #pragma unroll
                for (int ct = 0; ct < 4; ++ct) {
                    f32x4 acc = {0.f, 0.f, 0.f, 0.f};
                    acc = __builtin_amdgcn_mfma_f32_16x16x32_bf16(kf[ct][0], qf[qt][0], acc, 0, 0, 0);
                    acc = __builtin_amdgcn_mfma_f32_16x16x32_bf16(kf[ct][1], qf[qt][1], acc, 0, 0, 0);
                    st[ct] = acc;
                }
                __builtin_amdgcn_s_setprio(0);

                // in-register online softmax
                float mx = -1e30f;
                if (jb + 63 > qrow) {   // masking needed (wave/qt-uniform branch)
                    #pragma unroll
                    for (int ct = 0; ct < 4; ++ct)
                        #pragma unroll
                        for (int reg = 0; reg < 4; ++reg) {
                            const int key = jb + ct * 16 + g * 4 + reg;
                            const float sv = (key <= qrow) ? st[ct][reg] : -1e30f;
                            st[ct][reg] = sv;
                            mx = fmaxf(mx, sv);
                        }
                } else {
                    #pragma unroll
                    for (int ct = 0; ct < 4; ++ct) {
                        mx = fmaxf(mx, fmaxf(fmaxf(st[ct][0], st[ct][1]),
                                             fmaxf(st[ct][2], st[ct][3])));
                    }
                }
                mx = fmaxf(mx, __shfl_xor(mx, 16, 64));
                mx = fmaxf(mx, __shfl_xor(mx, 32, 64));
                const float mn = fmaxf(m[qt], mx);
                const float corr = __expf(m[qt] - mn);
                float rs = 0.f;
                #pragma unroll
                for (int ct = 0; ct < 4; ++ct)
                    #pragma unroll
                    for (int reg = 0; reg < 4; ++reg) {
                        const float p = __expf(st[ct][reg] - mn);
                        st[ct][reg] = p;
                        rs += p;
                    }
                rs += __shfl_xor(rs, 16, 64);
                rs += __shfl_xor(rs, 32, 64);
                l[qt] = l[qt] * corr + rs;
                m[qt] = mn;
                #pragma unroll
                for (int dt = 0; dt < 4; ++dt) {
                    oacc[qt][dt][0] *= corr; oacc[qt][dt][1] *= corr;
                    oacc[qt][dt][2] *= corr; oacc[qt][dt][3] *= corr;
                }

                // P^T -> per-wave LDS: row=qrow(c), key = ct*16 + g*4 + reg
                #pragma unroll
                for (int ct = 0; ct < 4; ++ct) {
                    uint2 u;
                    u.x = cvt_pk_bf16(st[ct][0], st[ct][1]);
                    u.y = cvt_pk_bf16(st[ct][2], st[ct][3]);
                    const int addr = (c * 128 + ct * 32 + g * 8) ^ ((c & 7) << 4);
                    *reinterpret_cast<uint2*>(PB + addr) = u;
                }
                // P^T B-fragments: col=c=qrow, k = ks*32 + g*8 + j
                short8 pf[2];
                #pragma unroll
                for (int ks = 0; ks < 2; ++ks) {
                    const int addr = (c * 128 + ks * 64 + g * 16) ^ ((c & 7) << 4);
                    pf[ks] = *reinterpret_cast<const short8*>(PB + addr);
                }
                // O^T += V^T · P^T : A=vf (row=c=d), B=pf (col=c=qrow)
                __builtin_amdgcn_s_setprio(1);
                #pragma unroll
                for (int dt = 0; dt < 4; ++dt) {
                    #pragma unroll
                    for (int ks = 0; ks < 2; ++ks) {
                        const int vd = dt * 16 + c;
                        const int addr = (vd * 128 + ks * 64 + g * 16) ^ ((vd & 7) << 4);
                        const short8 vf = *reinterpret_cast<const short8*>(Vsc + addr);
                        oacc[qt][dt] = __builtin_amdgcn_mfma_f32_16x16x32_bf16(vf, pf[ks], oacc[qt][dt], 0, 0, 0);
                    }
                }
                __builtin_amdgcn_s_setprio(0);
            }
        }
        __builtin_amdgcn_s_barrier();   // all waves done with buf before overwrite
    }

    // ---- epilogue: lane holds qrow = qt*16+c, d = dt*16 + g*4 + reg ----
    #pragma unroll
    for (int qt = 0; qt < 2; ++qt) {
        const int qrow = qb + w * 32 + qt * 16 + c;
        const float inv = 1.0f / l[qt];
        unsigned short* orow = att + (size_t)(b * N_ + qrow) * 1024 + h * 64;
        #pragma unroll
        for (int dt = 0; dt < 4; ++dt) {
            #pragma unroll
            for (int rp = 0; rp < 2; ++rp) {
                const unsigned u = cvt_pk_bf16(oacc[qt][dt][2 * rp] * inv,
                                               oacc[qt][dt][2 * rp + 1] * inv);
                *reinterpret_cast<unsigned*>(orow + dt * 16 + g * 4 + rp * 2) = u;
            }
        }
    }
}

extern "C" void kernel_launch(void* const* d_in, const int* in_sizes, int n_in,
                              void* d_out, int out_size, void* d_ws, size_t ws_size,
                              hipStream_t stream) {
    const float* x     = (const float*)d_in[0];
    const float* pos   = (const float*)d_in[1];
    const float* gamma = (const float*)d_in[2];
    const float* Wq    = (const float*)d_in[3];
    const float* Wkv   = (const float*)d_in[4];
    const float* Wo    = (const float*)d_in[5];
    const float* bo    = (const float*)d_in[6];
    float* out = (float*)d_out;
    char* ws = (char*)d_ws;

    const size_t MB = 1024 * 1024;
    unsigned short* kvb  = (unsigned short*)(ws);             // 16 MB
    unsigned short* qb   = (unsigned short*)(ws + 16 * MB);   // 8 MB
    unsigned short* xn_b = (unsigned short*)(ws + 24 * MB);   // 8 MB (reused as att)
    unsigned short* xb   = (unsigned short*)(ws + 32 * MB);   // 8 MB
    unsigned short* Wqt  = (unsigned short*)(ws + 40 * MB);   // 2 MB
    unsigned short* Wkvt = (unsigned short*)(ws + 42 * MB);   // 4 MB
    unsigned short* Wot  = (unsigned short*)(ws + 46 * MB);   // 2 MB
    unsigned short* vt   = (unsigned short*)(ws + 48 * MB);   // 8 MB
    unsigned short* att  = xn_b;

    convT_kernel<<<dim3(32, 32), 256, 0, stream>>>(Wq, Wqt, 1024, 1024);
    convT_kernel<<<dim3(64, 32), 256, 0, stream>>>(Wkv, Wkvt, 2048, 1024);
    convT_kernel<<<dim3(32, 32), 256, 0, stream>>>(Wo, Wot, 1024, 1024);

    rmsnorm_kernel<<<B_ * N_, 256, 0, stream>>>(x, gamma, xn_b, xb);

    gemm_bf16<64, false, true><<<dim3(16, 32), 256, 0, stream>>>(
        xn_b, Wqt, nullptr, qb, 4096, 1024, 1024);
    gemm_bf16<128, false, true><<<dim3(16, 32), 256, 0, stream>>>(
        xb, Wkvt, nullptr, kvb, 4096, 2048, 1024);

    rope_bf16_kernel<<<2048, 256, 0, stream>>>(qb, pos, 1024, 0.125f);
    rope_bf16_kernel<<<2048, 256, 0, stream>>>(kvb, pos, 2048, 1.0f);

    transposeV_kernel<<<dim3(32, 32), 256, 0, stream>>>(kvb, vt);

    attn_mfma_kernel<<<dim3(N_ / 128, B_ * H_), 256, 0, stream>>>(qb, kvb, vt, att);

    gemm_bf16<64, true, false><<<dim3(16, 32), 256, 0, stream>>>(
        att, Wot, bo, out, 4096, 1024, 1024);
}

// Round 6
// 171.452 us; speedup vs baseline: 8.7073x; 1.0773x over previous
//
#include <hip/hip_runtime.h>
#include <cmath>

#define B_ 2
#define N_ 2048
#define D_ 1024
#define H_ 16

typedef __attribute__((ext_vector_type(8))) short short8;
typedef __attribute__((ext_vector_type(4))) float f32x4;
typedef __attribute__((ext_vector_type(4))) unsigned short u16x4;

__device__ __forceinline__ unsigned short f2bf(float f) {
    union { float f; unsigned u; } x;
    x.f = f;
    unsigned r = x.u + 0x7FFFu + ((x.u >> 16) & 1u);
    return (unsigned short)(r >> 16);
}
__device__ __forceinline__ float bf2f(unsigned short u) {
    union { unsigned u; float f; } x;
    x.u = ((unsigned)u) << 16;
    return x.f;
}
__device__ __forceinline__ unsigned cvt_pk_bf16(float lo, float hi) {
    unsigned r;
    asm("v_cvt_pk_bf16_f32 %0, %1, %2" : "=v"(r) : "v"(lo), "v"(hi));
    return r;
}
__device__ __forceinline__ void gload_lds16(const void* g, void* l) {
    __builtin_amdgcn_global_load_lds((const __attribute__((address_space(1))) unsigned*)g,
                                     (__attribute__((address_space(3))) unsigned*)l,
                                     16, 0, 0);
}

// ---------------- RMS-like norm -> bf16 xn, plus bf16 copy of x ----------------
__global__ __launch_bounds__(256) void rmsnorm_kernel(const float* __restrict__ x,
                                                      const float* __restrict__ gamma,
                                                      unsigned short* __restrict__ xn,
                                                      unsigned short* __restrict__ xb) {
    const int row = blockIdx.x;
    const float4 v = reinterpret_cast<const float4*>(x + (size_t)row * D_)[threadIdx.x];
    float ss = v.x * v.x + v.y * v.y + v.z * v.z + v.w * v.w;
    #pragma unroll
    for (int off = 32; off; off >>= 1) ss += __shfl_xor(ss, off, 64);
    __shared__ float wss[4];
    if ((threadIdx.x & 63) == 0) wss[threadIdx.x >> 6] = ss;
    __syncthreads();
    const float tot = wss[0] + wss[1] + wss[2] + wss[3];
    const float inv = 1.0f / fmaxf(sqrtf(tot * (1.0f / D_)), 1e-8f);
    const float4 g = reinterpret_cast<const float4*>(gamma)[threadIdx.x];
    u16x4 on, ox;
    on[0] = f2bf(v.x * inv * g.x); on[1] = f2bf(v.y * inv * g.y);
    on[2] = f2bf(v.z * inv * g.z); on[3] = f2bf(v.w * inv * g.w);
    ox[0] = f2bf(v.x); ox[1] = f2bf(v.y); ox[2] = f2bf(v.z); ox[3] = f2bf(v.w);
    *reinterpret_cast<u16x4*>(xn + (size_t)row * D_ + threadIdx.x * 4) = on;
    *reinterpret_cast<u16x4*>(xb + (size_t)row * D_ + threadIdx.x * 4) = ox;
}

// ---------------- W (f32, [K][Nm]) -> W^T (bf16, [Nm][K]) ----------------
__global__ __launch_bounds__(256) void convT_kernel(const float* __restrict__ W,
                                                    unsigned short* __restrict__ Wt,
                                                    int Nm, int K) {
    __shared__ float tile[32][33];
    const int n0 = blockIdx.x * 32, k0 = blockIdx.y * 32;
    const int r = threadIdx.x >> 3, c4 = (threadIdx.x & 7) * 4;
    const float4 ld = *reinterpret_cast<const float4*>(W + (size_t)(k0 + r) * Nm + n0 + c4);
    tile[r][c4 + 0] = ld.x; tile[r][c4 + 1] = ld.y;
    tile[r][c4 + 2] = ld.z; tile[r][c4 + 3] = ld.w;
    __syncthreads();
    u16x4 o;
    #pragma unroll
    for (int j = 0; j < 4; ++j) o[j] = f2bf(tile[c4 + j][r]);
    *reinterpret_cast<u16x4*>(Wt + (size_t)(n0 + r) * K + k0 + c4) = o;
}

// ---------------- V half of kv -> Vt[bh][d][n] (bf16) ----------------
__global__ __launch_bounds__(256) void transposeV_kernel(const unsigned short* __restrict__ kv,
                                                         unsigned short* __restrict__ vt) {
    __shared__ unsigned short tile[64][72];
    const int bh = blockIdx.y;
    const int b = bh >> 4, h = bh & 15;
    const int n0 = blockIdx.x * 64;
    const int tid = threadIdx.x;
    const int r = tid >> 3, c = (tid & 7) * 8;
    #pragma unroll
    for (int i = 0; i < 2; ++i) {
        const int n = i * 32 + r;
        const short8 v = *reinterpret_cast<const short8*>(
            kv + (size_t)(b * N_ + n0 + n) * 2048 + 1024 + h * 64 + c);
        *reinterpret_cast<short8*>(&tile[n][c]) = v;
    }
    __syncthreads();
    #pragma unroll
    for (int i = 0; i < 2; ++i) {
        const int d = i * 32 + r;
        short8 o;
        #pragma unroll
        for (int j = 0; j < 8; ++j) o[j] = (short)tile[c + j][d];
        *reinterpret_cast<short8*>(vt + ((size_t)bh * 64 + d) * 2048 + n0 + c) = o;
    }
}

// ---------------- bf16 MFMA GEMM (unchanged) ----------------
template <int BN, bool BIAS, bool OUTBF>
__global__ __launch_bounds__(256) void gemm_bf16(const unsigned short* __restrict__ A,
                                                 const unsigned short* __restrict__ Bt,
                                                 const float* __restrict__ bias,
                                                 void* __restrict__ Cout,
                                                 int M, int Nmat, int K) {
    constexpr int WN = BN / 2;
    constexpr int NF = BN / 32;
    __shared__ unsigned short As[128 * 64];
    __shared__ unsigned short Bs[BN * 64];
    const int tid = threadIdx.x, lane = tid & 63, w = tid >> 6;
    const int m0 = blockIdx.y * 128, n0 = blockIdx.x * BN;
    const int wm = w >> 1, wn = w & 1;

    const int sr = tid >> 3;
    const int sc = (tid & 7) * 8;

    f32x4 acc[4][NF] = {};

    for (int k0 = 0; k0 < K; k0 += 64) {
        __syncthreads();
        #pragma unroll
        for (int i = 0; i < 4; ++i) {
            const int r = i * 32 + sr;
            const unsigned short* src = A + (size_t)(m0 + r) * K + k0 + (sc ^ ((r & 7) << 3));
            gload_lds16(src, (char*)As + i * 4096 + w * 1024);
        }
        #pragma unroll
        for (int i = 0; i < NF; ++i) {
            const int r = i * 32 + sr;
            const unsigned short* src = Bt + (size_t)(n0 + r) * K + k0 + (sc ^ ((r & 7) << 3));
            gload_lds16(src, (char*)Bs + i * 4096 + w * 1024);
        }
        __syncthreads();

        short8 af[4][2], bf[NF][2];
        #pragma unroll
        for (int mf = 0; mf < 4; ++mf)
            #pragma unroll
            for (int ks = 0; ks < 2; ++ks) {
                const int r = wm * 64 + mf * 16 + (lane & 15);
                const int cb = (ks * 64 + ((lane >> 4) * 16)) ^ ((r & 7) << 4);
                af[mf][ks] = *reinterpret_cast<const short8*>((const char*)As + r * 128 + cb);
            }
        #pragma unroll
        for (int nf = 0; nf < NF; ++nf)
            #pragma unroll
            for (int ks = 0; ks < 2; ++ks) {
                const int r = wn * WN + nf * 16 + (lane & 15);
                const int cb = (ks * 64 + ((lane >> 4) * 16)) ^ ((r & 7) << 4);
                bf[nf][ks] = *reinterpret_cast<const short8*>((const char*)Bs + r * 128 + cb);
            }
        #pragma unroll
        for (int ks = 0; ks < 2; ++ks)
            #pragma unroll
            for (int mf = 0; mf < 4; ++mf)
                #pragma unroll
                for (int nf = 0; nf < NF; ++nf)
                    acc[mf][nf] = __builtin_amdgcn_mfma_f32_16x16x32_bf16(af[mf][ks], bf[nf][ks], acc[mf][nf], 0, 0, 0);
    }

    float bb[NF];
    #pragma unroll
    for (int nf = 0; nf < NF; ++nf)
        bb[nf] = BIAS ? bias[n0 + wn * WN + nf * 16 + (lane & 15)] : 0.0f;

    #pragma unroll
    for (int mf = 0; mf < 4; ++mf)
        #pragma unroll
        for (int nf = 0; nf < NF; ++nf)
            #pragma unroll
            for (int reg = 0; reg < 4; ++reg) {
                const int row = m0 + wm * 64 + mf * 16 + (lane >> 4) * 4 + reg;
                const int col = n0 + wn * WN + nf * 16 + (lane & 15);
                const float val = acc[mf][nf][reg] + bb[nf];
                if (OUTBF)
                    ((unsigned short*)Cout)[(size_t)row * Nmat + col] = f2bf(val);
                else
                    ((float*)Cout)[(size_t)row * Nmat + col] = val;
            }
}

// ---------------- in-place RoPE on bf16 ----------------
__global__ __launch_bounds__(256) void rope_bf16_kernel(unsigned short* __restrict__ t,
                                                        const float* __restrict__ pos,
                                                        int row_len, float scale) {
    const int idx = blockIdx.x * 256 + threadIdx.x;
    const int d4 = (idx & 7) * 4;
    const int h = (idx >> 3) & 15;
    const int n = (idx >> 7) & (N_ - 1);
    const int b = idx >> 18;
    const size_t base = (size_t)(b * N_ + n) * row_len + h * 64;
    u16x4 u1 = *reinterpret_cast<u16x4*>(t + base + d4);
    u16x4 u2 = *reinterpret_cast<u16x4*>(t + base + 32 + d4);
    const float4 f1 = *reinterpret_cast<const float4*>(pos + n * 64 + d4);
    const float4 f2 = *reinterpret_cast<const float4*>(pos + n * 64 + 32 + d4);
    const float f1a[4] = {f1.x, f1.y, f1.z, f1.w};
    const float f2a[4] = {f2.x, f2.y, f2.z, f2.w};
    #pragma unroll
    for (int j = 0; j < 4; ++j) {
        const float x1 = bf2f(u1[j]), x2 = bf2f(u2[j]);
        u1[j] = f2bf(scale * (x1 * cosf(f1a[j]) - x2 * sinf(f1a[j])));
        u2[j] = f2bf(scale * (x2 * cosf(f2a[j]) + x1 * sinf(f2a[j])));
    }
    *reinterpret_cast<u16x4*>(t + base + d4) = u1;
    *reinterpret_cast<u16x4*>(t + base + 32 + d4) = u2;
}

// ---------------- bf16 MFMA causal flash attention (swapped-operand, 64-row q blocks) ----------------
// grid (N/64, B*H), qi reversed; 4 waves, wave w owns q rows qb + w*16 + (lane&15).
// S^T = mfma(K,Q): lane holds q-row = lane&15; key = jb + ct*16 + g*4 + reg. Softmax per-lane.
// O^T = mfma(V^T, P^T): oacc col = q-row, row = d.
__global__ __launch_bounds__(256, 4) void attn_mfma_kernel(const unsigned short* __restrict__ q,
                                                           const unsigned short* __restrict__ kv,
                                                           const unsigned short* __restrict__ vt,
                                                           unsigned short* __restrict__ att) {
    const int bh = blockIdx.y;
    const int b = bh >> 4, h = bh & 15;
    const int qi = gridDim.x - 1 - blockIdx.x;   // big causal blocks dispatch first
    const int qb = qi * 64;
    const int tid = threadIdx.x;
    const int lane = tid & 63;
    const int w = tid >> 6;
    const int c = lane & 15;     // q-row within wave tile (and d-row for vf)
    const int g = lane >> 4;

    __shared__ __align__(16) unsigned short Ks[2][64 * 64];   // [key][d] swizzled
    __shared__ __align__(16) unsigned short Vs[2][64 * 64];   // [d][key] swizzled
    __shared__ __align__(16) unsigned short Ps[4][1024];      // per-wave P^T staging (2KB)
    char* const PB = (char*)&Ps[w][0];

    // Q fragment (B operand): col=c=qrow, k = ks*32 + g*8 + j
    const int qrow = qb + w * 16 + c;
    short8 qf[2];
    {
        const unsigned short* qp = q + (size_t)(b * N_ + qrow) * 1024 + h * 64 + g * 8;
        qf[0] = *reinterpret_cast<const short8*>(qp);
        qf[1] = *reinterpret_cast<const short8*>(qp + 32);
    }

    float m = -1e30f, l = 0.f;
    f32x4 oacc[4] = {};   // [dt]: col=c=qrow, row=g*4+reg = d within dt

    const int nt = qi + 1;
    const int sr = tid >> 3, sc = (tid & 7) * 8;

    // ---- prologue: stage tile 0 into buf 0 ----
    #pragma unroll
    for (int i = 0; i < 2; ++i) {
        const int r = i * 32 + sr;
        const int cs = sc ^ ((r & 7) << 3);
        gload_lds16(kv + (size_t)(b * N_ + r) * 2048 + h * 64 + cs,
                    (char*)Ks[0] + i * 4096 + w * 1024);
        gload_lds16(vt + ((size_t)bh * 64 + r) * 2048 + cs,
                    (char*)Vs[0] + i * 4096 + w * 1024);
    }

    for (int t = 0; t < nt; ++t) {
        const int jb = t * 64;
        // issue next tile's loads (counted-vmcnt pipeline)
        {
            const int tn = (t + 1 < nt) ? t + 1 : t;
            const int jn = tn * 64;
            char* kd = (char*)Ks[(t + 1) & 1];
            char* vd = (char*)Vs[(t + 1) & 1];
            #pragma unroll
            for (int i = 0; i < 2; ++i) {
                const int r = i * 32 + sr;
                const int cs = sc ^ ((r & 7) << 3);
                gload_lds16(kv + (size_t)(b * N_ + jn + r) * 2048 + h * 64 + cs,
                            kd + i * 4096 + w * 1024);
                gload_lds16(vt + ((size_t)bh * 64 + r) * 2048 + jn + cs,
                            vd + i * 4096 + w * 1024);
            }
        }
        asm volatile("s_waitcnt vmcnt(4)" ::: "memory");
        __builtin_amdgcn_s_barrier();

        const char* Ksc = (const char*)Ks[t & 1];
        const char* Vsc = (const char*)Vs[t & 1];

        if (jb <= qb + w * 16 + 15) {   // wave-uniform skip of fully-masked tiles
            // S^T = K·Q^T
            f32x4 st[4];
            __builtin_amdgcn_s_setprio(1);
            #pragma unroll
            for (int ct = 0; ct < 4; ++ct) {
                const int key = ct * 16 + c;
                f32x4 acc = {0.f, 0.f, 0.f, 0.f};
                #pragma unroll
                for (int ks = 0; ks < 2; ++ks) {
                    const int addr = (key * 128 + ks * 64 + g * 16) ^ ((key & 7) << 4);
                    const short8 kf = *reinterpret_cast<const short8*>(Ksc + addr);
                    acc = __builtin_amdgcn_mfma_f32_16x16x32_bf16(kf, qf[ks], acc, 0, 0, 0);
                }
                st[ct] = acc;
            }
            __builtin_amdgcn_s_setprio(0);

            // in-register online softmax (lane owns row qrow)
            float mx = -1e30f;
            if (jb + 63 > qrow) {   // masking needed (diagonal block)
                #pragma unroll
                for (int ct = 0; ct < 4; ++ct)
                    #pragma unroll
                    for (int reg = 0; reg < 4; ++reg) {
                        const int key = jb + ct * 16 + g * 4 + reg;
                        const float sv = (key <= qrow) ? st[ct][reg] : -1e30f;
                        st[ct][reg] = sv;
                        mx = fmaxf(mx, sv);
                    }
            } else {
                #pragma unroll
                for (int ct = 0; ct < 4; ++ct)
                    mx = fmaxf(mx, fmaxf(fmaxf(st[ct][0], st[ct][1]),
                                         fmaxf(st[ct][2], st[ct][3])));
            }
            mx = fmaxf(mx, __shfl_xor(mx, 16, 64));
            mx = fmaxf(mx, __shfl_xor(mx, 32, 64));
            const float mn = fmaxf(m, mx);
            const float corr = __expf(m - mn);
            float rs = 0.f;
            #pragma unroll
            for (int ct = 0; ct < 4; ++ct)
                #pragma unroll
                for (int reg = 0; reg < 4; ++reg) {
                    const float p = __expf(st[ct][reg] - mn);
                    st[ct][reg] = p;
                    rs += p;
                }
            rs += __shfl_xor(rs, 16, 64);
            rs += __shfl_xor(rs, 32, 64);
            l = l * corr + rs;
            m = mn;
            #pragma unroll
            for (int dt = 0; dt < 4; ++dt) {
                oacc[dt][0] *= corr; oacc[dt][1] *= corr;
                oacc[dt][2] *= corr; oacc[dt][3] *= corr;
            }

            // P^T -> per-wave LDS: row=qrow(c), key = ct*16 + g*4 + reg
            #pragma unroll
            for (int ct = 0; ct < 4; ++ct) {
                uint2 u;
                u.x = cvt_pk_bf16(st[ct][0], st[ct][1]);
                u.y = cvt_pk_bf16(st[ct][2], st[ct][3]);
                const int addr = (c * 128 + ct * 32 + g * 8) ^ ((c & 7) << 4);
                *reinterpret_cast<uint2*>(PB + addr) = u;
            }
            // P^T B-fragments: col=c=qrow, k = ks*32 + g*8 + j
            short8 pf[2];
            #pragma unroll
            for (int ks = 0; ks < 2; ++ks) {
                const int addr = (c * 128 + ks * 64 + g * 16) ^ ((c & 7) << 4);
                pf[ks] = *reinterpret_cast<const short8*>(PB + addr);
            }
            // O^T += V^T · P^T
            __builtin_amdgcn_s_setprio(1);
            #pragma unroll
            for (int dt = 0; dt < 4; ++dt) {
                #pragma unroll
                for (int ks = 0; ks < 2; ++ks) {
                    const int vd = dt * 16 + c;
                    const int addr = (vd * 128 + ks * 64 + g * 16) ^ ((vd & 7) << 4);
                    const short8 vf = *reinterpret_cast<const short8*>(Vsc + addr);
                    oacc[dt] = __builtin_amdgcn_mfma_f32_16x16x32_bf16(vf, pf[ks], oacc[dt], 0, 0, 0);
                }
            }
            __builtin_amdgcn_s_setprio(0);
        }
        __builtin_amdgcn_s_barrier();   // all waves done with buf before overwrite
    }

    // ---- epilogue: lane holds qrow, d = dt*16 + g*4 + reg ----
    {
        const float inv = 1.0f / l;
        unsigned short* orow = att + (size_t)(b * N_ + qrow) * 1024 + h * 64;
        #pragma unroll
        for (int dt = 0; dt < 4; ++dt) {
            #pragma unroll
            for (int rp = 0; rp < 2; ++rp) {
                const unsigned u = cvt_pk_bf16(oacc[dt][2 * rp] * inv,
                                               oacc[dt][2 * rp + 1] * inv);
                *reinterpret_cast<unsigned*>(orow + dt * 16 + g * 4 + rp * 2) = u;
            }
        }
    }
}

extern "C" void kernel_launch(void* const* d_in, const int* in_sizes, int n_in,
                              void* d_out, int out_size, void* d_ws, size_t ws_size,
                              hipStream_t stream) {
    const float* x     = (const float*)d_in[0];
    const float* pos   = (const float*)d_in[1];
    const float* gamma = (const float*)d_in[2];
    const float* Wq    = (const float*)d_in[3];
    const float* Wkv   = (const float*)d_in[4];
    const float* Wo    = (const float*)d_in[5];
    const float* bo    = (const float*)d_in[6];
    float* out = (float*)d_out;
    char* ws = (char*)d_ws;

    const size_t MB = 1024 * 1024;
    unsigned short* kvb  = (unsigned short*)(ws);             // 16 MB
    unsigned short* qb   = (unsigned short*)(ws + 16 * MB);   // 8 MB
    unsigned short* xn_b = (unsigned short*)(ws + 24 * MB);   // 8 MB (reused as att)
    unsigned short* xb   = (unsigned short*)(ws + 32 * MB);   // 8 MB
    unsigned short* Wqt  = (unsigned short*)(ws + 40 * MB);   // 2 MB
    unsigned short* Wkvt = (unsigned short*)(ws + 42 * MB);   // 4 MB
    unsigned short* Wot  = (unsigned short*)(ws + 46 * MB);   // 2 MB
    unsigned short* vt   = (unsigned short*)(ws + 48 * MB);   // 8 MB
    unsigned short* att  = xn_b;

    convT_kernel<<<dim3(32, 32), 256, 0, stream>>>(Wq, Wqt, 1024, 1024);
    convT_kernel<<<dim3(64, 32), 256, 0, stream>>>(Wkv, Wkvt, 2048, 1024);
    convT_kernel<<<dim3(32, 32), 256, 0, stream>>>(Wo, Wot, 1024, 1024);

    rmsnorm_kernel<<<B_ * N_, 256, 0, stream>>>(x, gamma, xn_b, xb);

    gemm_bf16<64, false, true><<<dim3(16, 32), 256, 0, stream>>>(
        xn_b, Wqt, nullptr, qb, 4096, 1024, 1024);
    gemm_bf16<128, false, true><<<dim3(16, 32), 256, 0, stream>>>(
        xb, Wkvt, nullptr, kvb, 4096, 2048, 1024);

    rope_bf16_kernel<<<2048, 256, 0, stream>>>(qb, pos, 1024, 0.125f);
    rope_bf16_kernel<<<2048, 256, 0, stream>>>(kvb, pos, 2048, 1.0f);

    transposeV_kernel<<<dim3(32, 32), 256, 0, stream>>>(kvb, vt);

    attn_mfma_kernel<<<dim3(N_ / 64, B_ * H_), 256, 0, stream>>>(qb, kvb, vt, att);

    gemm_bf16<64, true, false><<<dim3(16, 32), 256, 0, stream>>>(
        att, Wot, bo, out, 4096, 1024, 1024);
}

// Round 7
// 157.767 us; speedup vs baseline: 9.4626x; 1.0867x over previous
//
#include <hip/hip_runtime.h>
#include <cmath>

#define B_ 2
#define N_ 2048
#define D_ 1024
#define H_ 16

typedef __attribute__((ext_vector_type(8))) short short8;
typedef __attribute__((ext_vector_type(4))) float f32x4;
typedef __attribute__((ext_vector_type(4))) unsigned short u16x4;

__device__ __forceinline__ unsigned short f2bf(float f) {
    union { float f; unsigned u; } x;
    x.f = f;
    unsigned r = x.u + 0x7FFFu + ((x.u >> 16) & 1u);
    return (unsigned short)(r >> 16);
}
__device__ __forceinline__ unsigned cvt_pk_bf16(float lo, float hi) {
    unsigned r;
    asm("v_cvt_pk_bf16_f32 %0, %1, %2" : "=v"(r) : "v"(lo), "v"(hi));
    return r;
}
__device__ __forceinline__ float exp2_fast(float x) {
    float r;
    asm("v_exp_f32 %0, %1" : "=v"(r) : "v"(x));
    return r;
}
__device__ __forceinline__ void gload_lds16(const void* g, void* l) {
    __builtin_amdgcn_global_load_lds((const __attribute__((address_space(1))) unsigned*)g,
                                     (__attribute__((address_space(3))) unsigned*)l,
                                     16, 0, 0);
}

// ---------------- cos/sin tables (trig once; q table pre-scaled by 0.125*log2e) ----------------
__global__ __launch_bounds__(256) void freqtab_kernel(const float* __restrict__ pos,
                                                      float2* __restrict__ tabq,
                                                      float2* __restrict__ tabk) {
    const int idx = blockIdx.x * 256 + threadIdx.x;   // N_*64 = 131072
    const float f = pos[idx];
    const float cc = cosf(f), ss = sinf(f);
    const float sq = 0.125f * 1.4426950408889634f;    // DH^-0.5 * log2(e)
    tabq[idx] = make_float2(sq * cc, sq * ss);
    tabk[idx] = make_float2(cc, ss);
}

// ---------------- RMS-like norm -> bf16 xn, plus bf16 copy of x ----------------
__global__ __launch_bounds__(256) void rmsnorm_kernel(const float* __restrict__ x,
                                                      const float* __restrict__ gamma,
                                                      unsigned short* __restrict__ xn,
                                                      unsigned short* __restrict__ xb) {
    const int row = blockIdx.x;
    const float4 v = reinterpret_cast<const float4*>(x + (size_t)row * D_)[threadIdx.x];
    float ss = v.x * v.x + v.y * v.y + v.z * v.z + v.w * v.w;
    #pragma unroll
    for (int off = 32; off; off >>= 1) ss += __shfl_xor(ss, off, 64);
    __shared__ float wss[4];
    if ((threadIdx.x & 63) == 0) wss[threadIdx.x >> 6] = ss;
    __syncthreads();
    const float tot = wss[0] + wss[1] + wss[2] + wss[3];
    const float inv = 1.0f / fmaxf(sqrtf(tot * (1.0f / D_)), 1e-8f);
    const float4 g = reinterpret_cast<const float4*>(gamma)[threadIdx.x];
    u16x4 on, ox;
    on[0] = f2bf(v.x * inv * g.x); on[1] = f2bf(v.y * inv * g.y);
    on[2] = f2bf(v.z * inv * g.z); on[3] = f2bf(v.w * inv * g.w);
    ox[0] = f2bf(v.x); ox[1] = f2bf(v.y); ox[2] = f2bf(v.z); ox[3] = f2bf(v.w);
    *reinterpret_cast<u16x4*>(xn + (size_t)row * D_ + threadIdx.x * 4) = on;
    *reinterpret_cast<u16x4*>(xb + (size_t)row * D_ + threadIdx.x * 4) = ox;
}

// ---------------- all 3 weight transposes in one kernel ----------------
__global__ __launch_bounds__(256) void convT_all_kernel(const float* __restrict__ Wq,
                                                        const float* __restrict__ Wkv,
                                                        const float* __restrict__ Wo,
                                                        unsigned short* __restrict__ Wqt,
                                                        unsigned short* __restrict__ Wkvt,
                                                        unsigned short* __restrict__ Wot) {
    __shared__ float tile[32][33];
    const int bx = blockIdx.x;   // 0..127 over concat {Wq:32, Wkv:64, Wo:32}
    const float* W;
    unsigned short* Wt;
    int Nm, n0;
    if (bx < 32)       { W = Wq;  Wt = Wqt;  Nm = 1024; n0 = bx * 32; }
    else if (bx < 96)  { W = Wkv; Wt = Wkvt; Nm = 2048; n0 = (bx - 32) * 32; }
    else               { W = Wo;  Wt = Wot;  Nm = 1024; n0 = (bx - 96) * 32; }
    const int k0 = blockIdx.y * 32;
    const int r = threadIdx.x >> 3, c4 = (threadIdx.x & 7) * 4;
    const float4 ld = *reinterpret_cast<const float4*>(W + (size_t)(k0 + r) * Nm + n0 + c4);
    tile[r][c4 + 0] = ld.x; tile[r][c4 + 1] = ld.y;
    tile[r][c4 + 2] = ld.z; tile[r][c4 + 3] = ld.w;
    __syncthreads();
    u16x4 o;
    #pragma unroll
    for (int j = 0; j < 4; ++j) o[j] = f2bf(tile[c4 + j][r]);
    *reinterpret_cast<u16x4*>(Wt + (size_t)(n0 + r) * 1024 + k0 + c4) = o;
}

// ---------------- V half (vb) -> Vt[bh][d][n] (bf16) ----------------
__global__ __launch_bounds__(256) void transposeV_kernel(const unsigned short* __restrict__ vb,
                                                         unsigned short* __restrict__ vt) {
    __shared__ unsigned short tile[64][72];
    const int bh = blockIdx.y;
    const int b = bh >> 4, h = bh & 15;
    const int n0 = blockIdx.x * 64;
    const int tid = threadIdx.x;
    const int r = tid >> 3, c = (tid & 7) * 8;
    #pragma unroll
    for (int i = 0; i < 2; ++i) {
        const int n = i * 32 + r;
        const short8 v = *reinterpret_cast<const short8*>(
            vb + (size_t)(b * N_ + n0 + n) * 1024 + h * 64 + c);
        *reinterpret_cast<short8*>(&tile[n][c]) = v;
    }
    __syncthreads();
    #pragma unroll
    for (int i = 0; i < 2; ++i) {
        const int d = i * 32 + r;
        short8 o;
        #pragma unroll
        for (int j = 0; j < 8; ++j) o[j] = (short)tile[c + j][d];
        *reinterpret_cast<short8*>(vt + ((size_t)bh * 64 + d) * 2048 + n0 + c) = o;
    }
}

// ---------------- bf16 MFMA GEMM ----------------
// MODE 0: f32 out + bias (BN=64). MODE 2: rope epilogue -> bf16 Cout (q). MODE 3: kv split —
// blocks x<8 write roped K to Cout (kb), x>=8 write plain V to Cout2 (vb). All dst stride 1024.
template <int BN, int MODE>
__global__ __launch_bounds__(256) void gemm_bf16(const unsigned short* __restrict__ A,
                                                 const unsigned short* __restrict__ Bt,
                                                 const float* __restrict__ bias,
                                                 void* __restrict__ Cout,
                                                 void* __restrict__ Cout2,
                                                 const float2* __restrict__ tab,
                                                 int K) {
    constexpr int WN = BN / 2;
    constexpr int NF = BN / 32;
    __shared__ unsigned short As[128 * 64];
    __shared__ unsigned short Bs[BN * 64];
    const int tid = threadIdx.x, lane = tid & 63, w = tid >> 6;
    const int m0 = blockIdx.y * 128, n0 = blockIdx.x * BN;
    const int wm = w >> 1, wn = w & 1;
    const int cc = lane & 15;

    const int sr = tid >> 3;
    const int sc = (tid & 7) * 8;

    f32x4 acc[4][NF] = {};

    for (int k0 = 0; k0 < K; k0 += 64) {
        __syncthreads();
        #pragma unroll
        for (int i = 0; i < 4; ++i) {
            const int r = i * 32 + sr;
            const unsigned short* src = A + (size_t)(m0 + r) * K + k0 + (sc ^ ((r & 7) << 3));
            gload_lds16(src, (char*)As + i * 4096 + w * 1024);
        }
        #pragma unroll
        for (int i = 0; i < NF; ++i) {
            const int r = i * 32 + sr;
            const unsigned short* src = Bt + (size_t)(n0 + r) * K + k0 + (sc ^ ((r & 7) << 3));
            gload_lds16(src, (char*)Bs + i * 4096 + w * 1024);
        }
        __syncthreads();

        short8 af[4][2], bf[NF][2];
        #pragma unroll
        for (int mf = 0; mf < 4; ++mf)
            #pragma unroll
            for (int ks = 0; ks < 2; ++ks) {
                const int r = wm * 64 + mf * 16 + cc;
                const int cb = (ks * 64 + ((lane >> 4) * 16)) ^ ((r & 7) << 4);
                af[mf][ks] = *reinterpret_cast<const short8*>((const char*)As + r * 128 + cb);
            }
        #pragma unroll
        for (int nf = 0; nf < NF; ++nf)
            #pragma unroll
            for (int ks = 0; ks < 2; ++ks) {
                const int r = wn * WN + nf * 16 + cc;
                const int cb = (ks * 64 + ((lane >> 4) * 16)) ^ ((r & 7) << 4);
                bf[nf][ks] = *reinterpret_cast<const short8*>((const char*)Bs + r * 128 + cb);
            }
        #pragma unroll
        for (int ks = 0; ks < 2; ++ks)
            #pragma unroll
            for (int mf = 0; mf < 4; ++mf)
                #pragma unroll
                for (int nf = 0; nf < NF; ++nf)
                    acc[mf][nf] = __builtin_amdgcn_mfma_f32_16x16x32_bf16(af[mf][ks], bf[nf][ks], acc[mf][nf], 0, 0, 0);
    }

    if (MODE == 0) {
        float bb[NF];
        #pragma unroll
        for (int nf = 0; nf < NF; ++nf)
            bb[nf] = bias[n0 + wn * WN + nf * 16 + cc];
        #pragma unroll
        for (int mf = 0; mf < 4; ++mf)
            #pragma unroll
            for (int nf = 0; nf < NF; ++nf)
                #pragma unroll
                for (int reg = 0; reg < 4; ++reg) {
                    const int row = m0 + wm * 64 + mf * 16 + (lane >> 4) * 4 + reg;
                    const int col = n0 + wn * WN + nf * 16 + cc;
                    ((float*)Cout)[(size_t)row * 1024 + col] = acc[mf][nf][reg] + bb[nf];
                }
    } else if (MODE == 3 && blockIdx.x >= 8) {
        // V half: plain bf16 -> Cout2 (vb), col - 1024
        #pragma unroll
        for (int mf = 0; mf < 4; ++mf)
            #pragma unroll
            for (int nf = 0; nf < NF; ++nf)
                #pragma unroll
                for (int reg = 0; reg < 4; ++reg) {
                    const int row = m0 + wm * 64 + mf * 16 + (lane >> 4) * 4 + reg;
                    const int col = n0 + wn * WN + nf * 16 + cc - 1024;
                    ((unsigned short*)Cout2)[(size_t)row * 1024 + col] = f2bf(acc[mf][nf][reg]);
                }
    } else {
        // rope epilogue (q, or K half of kv): pairs (d, d+32) = (nf, nf+2), head-local d = nf*16+cc
        #pragma unroll
        for (int mf = 0; mf < 4; ++mf)
            #pragma unroll
            for (int reg = 0; reg < 4; ++reg) {
                const int row = m0 + wm * 64 + mf * 16 + (lane >> 4) * 4 + reg;
                const int n = row & (N_ - 1);
                #pragma unroll
                for (int nf = 0; nf < 2; ++nf) {
                    const int d = nf * 16 + cc;
                    const float2 t1 = tab[n * 64 + d];
                    const float2 t2 = tab[n * 64 + 32 + d];
                    const float x1 = acc[mf][nf][reg];
                    const float x2 = acc[mf][nf + 2][reg];
                    const float o1 = x1 * t1.x - x2 * t1.y;
                    const float o2 = x2 * t2.x + x1 * t2.y;
                    const int col = n0 + wn * WN + nf * 16 + cc;
                    ((unsigned short*)Cout)[(size_t)row * 1024 + col] = f2bf(o1);
                    ((unsigned short*)Cout)[(size_t)row * 1024 + col + 32] = f2bf(o2);
                }
            }
    }
}

// ---------------- bf16 MFMA causal flash attention ----------------
// exp2-domain softmax (q pre-scaled by 0.125*log2e), defer-max (THR=8),
// K double-buffered, V single-buffered (issued post-barrier, hides under next QK^T).
__global__ __launch_bounds__(256, 5) void attn_mfma_kernel(const unsigned short* __restrict__ q,
                                                           const unsigned short* __restrict__ kb,
                                                           const unsigned short* __restrict__ vt,
                                                           unsigned short* __restrict__ att) {
    const int bh = blockIdx.y;
    const int b = bh >> 4, h = bh & 15;
    const int qi = gridDim.x - 1 - blockIdx.x;   // big causal blocks dispatch first
    const int qb = qi * 64;
    const int tid = threadIdx.x;
    const int lane = tid & 63;
    const int w = tid >> 6;
    const int c = lane & 15;
    const int g = lane >> 4;

    __shared__ __align__(16) unsigned short Ks[2][64 * 64];   // [key][d] swizzled (dbuf)
    __shared__ __align__(16) unsigned short Vs[64 * 64];      // [d][key] swizzled (single)
    __shared__ __align__(16) unsigned short Ps[4][1024];      // per-wave P^T staging
    char* const PB = (char*)&Ps[w][0];

    const int qrow = qb + w * 16 + c;
    short8 qf[2];
    {
        const unsigned short* qp = q + (size_t)(b * N_ + qrow) * 1024 + h * 64 + g * 8;
        qf[0] = *reinterpret_cast<const short8*>(qp);
        qf[1] = *reinterpret_cast<const short8*>(qp + 32);
    }

    float m = -1e30f, l = 0.f;
    f32x4 oacc[4] = {};

    const int nt = qi + 1;
    const int sr = tid >> 3, sc = (tid & 7) * 8;
    const unsigned short* kbase = kb + (size_t)b * N_ * 1024 + h * 64;
    const unsigned short* vbase = vt + (size_t)bh * 64 * 2048;

    // prologue: stage K0 + V0
    #pragma unroll
    for (int i = 0; i < 2; ++i) {
        const int r = i * 32 + sr;
        const int cs = sc ^ ((r & 7) << 3);
        gload_lds16(kbase + (size_t)r * 1024 + cs, (char*)Ks[0] + i * 4096 + w * 1024);
        gload_lds16(vbase + (size_t)r * 2048 + cs, (char*)Vs + i * 4096 + w * 1024);
    }

    for (int t = 0; t < nt; ++t) {
        const int jb = t * 64;
        const int jn = jb + 64;
        if (t + 1 < nt) {
            char* kd = (char*)Ks[(t + 1) & 1];
            #pragma unroll
            for (int i = 0; i < 2; ++i) {
                const int r = i * 32 + sr;
                const int cs = sc ^ ((r & 7) << 3);
                gload_lds16(kbase + (size_t)(jn + r) * 1024 + cs, kd + i * 4096 + w * 1024);
            }
            asm volatile("s_waitcnt vmcnt(2)" ::: "memory");  // own K[t],V[t] landed; K[t+1] flying
        } else {
            asm volatile("s_waitcnt vmcnt(0)" ::: "memory");
        }
        __builtin_amdgcn_s_barrier();

        const char* Ksc = (const char*)Ks[t & 1];
        const char* Vsc = (const char*)Vs;

        if (jb <= qb + w * 16 + 15) {   // wave-uniform skip of fully-masked tiles
            // S^T = K·Q^T
            f32x4 st[4];
            __builtin_amdgcn_s_setprio(1);
            #pragma unroll
            for (int ct = 0; ct < 4; ++ct) {
                const int key = ct * 16 + c;
                f32x4 acc = {0.f, 0.f, 0.f, 0.f};
                #pragma unroll
                for (int ks = 0; ks < 2; ++ks) {
                    const int addr = (key * 128 + ks * 64 + g * 16) ^ ((key & 7) << 4);
                    const short8 kf = *reinterpret_cast<const short8*>(Ksc + addr);
                    acc = __builtin_amdgcn_mfma_f32_16x16x32_bf16(kf, qf[ks], acc, 0, 0, 0);
                }
                st[ct] = acc;
            }
            __builtin_amdgcn_s_setprio(0);

            // exp2-domain online softmax with defer-max
            float mx = -1e30f;
            if (jb + 63 > qrow) {
                #pragma unroll
                for (int ct = 0; ct < 4; ++ct)
                    #pragma unroll
                    for (int reg = 0; reg < 4; ++reg) {
                        const int key = jb + ct * 16 + g * 4 + reg;
                        const float sv = (key <= qrow) ? st[ct][reg] : -1e30f;
                        st[ct][reg] = sv;
                        mx = fmaxf(mx, sv);
                    }
            } else {
                #pragma unroll
                for (int ct = 0; ct < 4; ++ct)
                    mx = fmaxf(mx, fmaxf(fmaxf(st[ct][0], st[ct][1]),
                                         fmaxf(st[ct][2], st[ct][3])));
            }
            mx = fmaxf(mx, __shfl_xor(mx, 16, 64));
            mx = fmaxf(mx, __shfl_xor(mx, 32, 64));
            if (!__all(mx <= m + 8.0f)) {
                const float mn = fmaxf(m, mx);
                const float corr = exp2_fast(m - mn);
                l *= corr;
                m = mn;
                #pragma unroll
                for (int dt = 0; dt < 4; ++dt) {
                    oacc[dt][0] *= corr; oacc[dt][1] *= corr;
                    oacc[dt][2] *= corr; oacc[dt][3] *= corr;
                }
            }
            float rs = 0.f;
            #pragma unroll
            for (int ct = 0; ct < 4; ++ct)
                #pragma unroll
                for (int reg = 0; reg < 4; ++reg) {
                    const float p = exp2_fast(st[ct][reg] - m);
                    st[ct][reg] = p;
                    rs += p;
                }
            rs += __shfl_xor(rs, 16, 64);
            rs += __shfl_xor(rs, 32, 64);
            l += rs;

            // P^T -> per-wave LDS
            #pragma unroll
            for (int ct = 0; ct < 4; ++ct) {
                uint2 u;
                u.x = cvt_pk_bf16(st[ct][0], st[ct][1]);
                u.y = cvt_pk_bf16(st[ct][2], st[ct][3]);
                const int addr = (c * 128 + ct * 32 + g * 8) ^ ((c & 7) << 4);
                *reinterpret_cast<uint2*>(PB + addr) = u;
            }
            short8 pf[2];
            #pragma unroll
            for (int ks = 0; ks < 2; ++ks) {
                const int addr = (c * 128 + ks * 64 + g * 16) ^ ((c & 7) << 4);
                pf[ks] = *reinterpret_cast<const short8*>(PB + addr);
            }
            // O^T += V^T · P^T
            __builtin_amdgcn_s_setprio(1);
            #pragma unroll
            for (int dt = 0; dt < 4; ++dt) {
                #pragma unroll
                for (int ks = 0; ks < 2; ++ks) {
                    const int vd = dt * 16 + c;
                    const int addr = (vd * 128 + ks * 64 + g * 16) ^ ((vd & 7) << 4);
                    const short8 vf = *reinterpret_cast<const short8*>(Vsc + addr);
                    oacc[dt] = __builtin_amdgcn_mfma_f32_16x16x32_bf16(vf, pf[ks], oacc[dt], 0, 0, 0);
                }
            }
            __builtin_amdgcn_s_setprio(0);
        }
        __builtin_amdgcn_s_barrier();   // all waves done reading Vs / this K buf

        if (t + 1 < nt) {   // stage V[t+1] into the single V buffer
            #pragma unroll
            for (int i = 0; i < 2; ++i) {
                const int r = i * 32 + sr;
                const int cs = sc ^ ((r & 7) << 3);
                gload_lds16(vbase + (size_t)r * 2048 + jn + cs, (char*)Vs + i * 4096 + w * 1024);
            }
        }
    }

    // epilogue: lane holds qrow, d = dt*16 + g*4 + reg
    {
        const float inv = 1.0f / l;
        unsigned short* orow = att + (size_t)(b * N_ + qrow) * 1024 + h * 64;
        #pragma unroll
        for (int dt = 0; dt < 4; ++dt) {
            #pragma unroll
            for (int rp = 0; rp < 2; ++rp) {
                const unsigned u = cvt_pk_bf16(oacc[dt][2 * rp] * inv,
                                               oacc[dt][2 * rp + 1] * inv);
                *reinterpret_cast<unsigned*>(orow + dt * 16 + g * 4 + rp * 2) = u;
            }
        }
    }
}

extern "C" void kernel_launch(void* const* d_in, const int* in_sizes, int n_in,
                              void* d_out, int out_size, void* d_ws, size_t ws_size,
                              hipStream_t stream) {
    const float* x     = (const float*)d_in[0];
    const float* pos   = (const float*)d_in[1];
    const float* gamma = (const float*)d_in[2];
    const float* Wq    = (const float*)d_in[3];
    const float* Wkv   = (const float*)d_in[4];
    const float* Wo    = (const float*)d_in[5];
    const float* bo    = (const float*)d_in[6];
    float* out = (float*)d_out;
    char* ws = (char*)d_ws;

    const size_t MB = 1024 * 1024;
    unsigned short* kb   = (unsigned short*)(ws);             // 8 MB roped K [row][1024]
    unsigned short* vb   = (unsigned short*)(ws + 8 * MB);    // 8 MB V [row][1024]
    unsigned short* qb   = (unsigned short*)(ws + 16 * MB);   // 8 MB roped+scaled Q
    unsigned short* xn_b = (unsigned short*)(ws + 24 * MB);   // 8 MB (reused as att)
    unsigned short* xb   = (unsigned short*)(ws + 32 * MB);   // 8 MB
    unsigned short* Wqt  = (unsigned short*)(ws + 40 * MB);   // 2 MB
    unsigned short* Wkvt = (unsigned short*)(ws + 42 * MB);   // 4 MB
    unsigned short* Wot  = (unsigned short*)(ws + 46 * MB);   // 2 MB
    unsigned short* vt   = (unsigned short*)(ws + 48 * MB);   // 8 MB V^T [bh][d][n]
    float2* tabq         = (float2*)(ws + 56 * MB);           // 1 MB
    float2* tabk         = (float2*)(ws + 57 * MB);           // 1 MB
    unsigned short* att  = xn_b;

    freqtab_kernel<<<512, 256, 0, stream>>>(pos, tabq, tabk);
    convT_all_kernel<<<dim3(128, 32), 256, 0, stream>>>(Wq, Wkv, Wo, Wqt, Wkvt, Wot);
    rmsnorm_kernel<<<B_ * N_, 256, 0, stream>>>(x, gamma, xn_b, xb);

    gemm_bf16<128, 2><<<dim3(8, 32), 256, 0, stream>>>(
        xn_b, Wqt, nullptr, qb, nullptr, tabq, 1024);
    gemm_bf16<128, 3><<<dim3(16, 32), 256, 0, stream>>>(
        xb, Wkvt, nullptr, kb, vb, tabk, 1024);

    transposeV_kernel<<<dim3(32, 32), 256, 0, stream>>>(vb, vt);

    attn_mfma_kernel<<<dim3(N_ / 64, B_ * H_), 256, 0, stream>>>(qb, kb, vt, att);

    gemm_bf16<64, 0><<<dim3(16, 32), 256, 0, stream>>>(
        att, Wot, bo, out, nullptr, nullptr, 1024);
}